// Round 9
// baseline (7867.144 us; speedup 1.0000x reference)
//
#include <hip/hip_runtime.h>
#include <hip/hip_fp16.h>
#include <math.h>

#define BB 512
#define HH 256
#define SS 168
#define TT 24
#define NBLK 256
#define NTHR 256
typedef unsigned long long ull;
typedef unsigned short u16;
#define BH 131072ull  // 512*256

// ---- int area (from ws): per-group flags at ib + g*1024 ----
//   ife[0..168] tgt 32 | ifa 704+t tgt 32 | ifh0 736+t tgt 16 | ifh1 768+t tgt 16 | ifp 900 tgt 32
// ---- float offsets from fb = (float*)ws + 65536 ----
// y0 262144 | h1 262144 | h0 262144 (slot1=zb) | ctx 147456
// W0 2x[1024][320]u16 = 327680 fl | W1 6x[1024][512]u16 = 1572864 fl
// wp 1024 | wdT 65536 | bp 4096 | E16 11010048 | P16 11010048 -> total 24925184 fl
#define O_Y0  0ull
#define O_H1  262144ull
#define O_H0  524288ull
#define O_CTX 786432ull   // 512 x 288 (cols 0..255 ctx, col 256 pred)
#define O_W0  933888ull   // whi0 [1024][320] bf16, wlo0 follows (163840 fl each)
#define O_W1  1261568ull  // bf16 planes [1024][512]: whi1,wlo1,dhi0,dlo0,dhi1,dlo1 (262144 fl each)
#define O_WP  2834432ull  // dec cell0 pred column [1024] f32
#define O_WDT 2835456ull  // Wd^T [256][256] f32
#define O_BP  2900992ull  // packed biases 4x1024 (e0,e1,d0,d1)
#define O_E16 2905088ull  // half[512][168][256]
#define O_P16 13915136ull // half[512][168][256]

typedef float f32x4 __attribute__((ext_vector_type(4)));
typedef float v2f __attribute__((ext_vector_type(2)));
typedef unsigned int ru4 __attribute__((ext_vector_type(4)));  // 8 bf16 raw (4 VGPR)

__device__ __forceinline__ float sigf(float x) { return 1.f / (1.f + expf(-x)); }

#define AR __ATOMIC_RELAXED
#define SCA __HIP_MEMORY_SCOPE_AGENT
__device__ __forceinline__ int aLd(int* p) { return __hip_atomic_load(p, AR, SCA); }
__device__ __forceinline__ int aAdd(int* p, int v) { return __hip_atomic_fetch_add(p, v, AR, SCA); }

// ---- UC transport: relaxed agent-scope (coherence-point) ops, no fences ----
__device__ __forceinline__ float2 ld2(const float* p) {
  ull raw = __hip_atomic_load((const ull*)p, AR, SCA);
  float2 v; v.x = __uint_as_float((unsigned)raw); v.y = __uint_as_float((unsigned)(raw >> 32));
  return v;
}
__device__ __forceinline__ float ld1(const float* p) {
  unsigned raw = __hip_atomic_load((const unsigned*)p, AR, SCA);
  return __uint_as_float(raw);
}
__device__ __forceinline__ void st1(float* p, float v) {
  __hip_atomic_store((unsigned*)p, __float_as_uint(v), AR, SCA);
}
__device__ __forceinline__ void sth(__half* p, __half v) {
  __hip_atomic_store((unsigned short*)p, __half_as_ushort(v), AR, SCA);
}
__device__ __forceinline__ void stu(unsigned* p, unsigned v) {
  __hip_atomic_store(p, v, AR, SCA);
}

// ---- manual-vmcnt loads (r0/r7-proven pattern: asm + "memory" clobber) ----
__device__ __forceinline__ void ld_h(const float* p, v2f& a, v2f& b) {
  asm volatile("global_load_dwordx2 %0, %2, off sc0 sc1\n\t"
               "global_load_dwordx2 %1, %3, off sc0 sc1"
               : "=&v"(a), "=&v"(b) : "v"(p), "v"(p + 16) : "memory");
}
struct W4 { ru4 v[4]; };
__device__ __forceinline__ void ld_w4(const u16* ph, const u16* pl, W4& w) {
  asm volatile("global_load_dwordx4 %0, %4, off\n\t"
               "global_load_dwordx4 %1, %5, off\n\t"
               "global_load_dwordx4 %2, %6, off\n\t"
               "global_load_dwordx4 %3, %7, off"
               : "=&v"(w.v[0]), "=&v"(w.v[1]), "=&v"(w.v[2]), "=&v"(w.v[3])
               : "v"(ph), "v"(ph + 8), "v"(pl), "v"(pl + 8) : "memory");
}
#define VMW(n) asm volatile("s_waitcnt vmcnt(" #n ")" ::: "memory")

// inline-asm MFMA (r4/r6/r7-proven): D(=C) += A*B; VGPR C/D ok on gfx950.
#define MFMA(d, a, b) asm volatile("v_mfma_f32_16x16x32_bf16 %0, %1, %2, %0" \
                                   : "+v"(d) : "v"(a), "v"(b))
// force value materialization (compiler emits its waitcnt HERE, before our asm loads)
#define TOUCH(x) asm volatile("" : "+v"(x))

// ---- flag sync: no fences; data at coherence point before arrive ----
__device__ __forceinline__ void poll(int* f, int tgt) {
  while (aLd(f) < tgt) __builtin_amdgcn_s_sleep(1);
}
__device__ __forceinline__ void flag_arrive(int* f) {
  asm volatile("s_waitcnt vmcnt(0)" ::: "memory");
  __syncthreads();
  if (threadIdx.x == 0) aAdd(f, 1);
}
__device__ __forceinline__ void flag_wait2(int* f0, int t0, int* f1, int t1) {
  if (threadIdx.x == 0 && f0) poll(f0, t0);
  if (threadIdx.x == 64 && f1) poll(f1, t1);
  __syncthreads();
}

// ---- LDS ----
struct SMT {
  union {
    struct { unsigned WsH[128][20]; unsigned WsL[128][20]; float Ht[32][36]; } m;  // mfma gemm
    struct { float As[32][65];  float Bs[32][65]; } g;   // enc_proj gemm
    struct { float h1s[256], qs[256], vs[256], sc[192], ctxs[512], sred[4]; } at;
  };
};

__device__ __forceinline__ void fma16(float acc[4][4], const float4 hv, const float4 wv) {
  acc[0][0] += hv.x * wv.x; acc[0][1] += hv.x * wv.y; acc[0][2] += hv.x * wv.z; acc[0][3] += hv.x * wv.w;
  acc[1][0] += hv.y * wv.x; acc[1][1] += hv.y * wv.y; acc[1][2] += hv.y * wv.z; acc[1][3] += hv.y * wv.w;
  acc[2][0] += hv.z * wv.x; acc[2][1] += hv.z * wv.y; acc[2][2] += hv.z * wv.z; acc[2][3] += hv.z * wv.w;
  acc[3][0] += hv.w * wv.x; acc[3][1] += hv.w * wv.y; acc[3][2] += hv.w * wv.z; acc[3][3] += hv.w * wv.w;
}

// ---- fp32 -> bf16 hi/lo split, RNE (unbiased; dropped lo*lo ~2^-18 relative) ----
__device__ __forceinline__ unsigned rne16(unsigned u) {
  return (u + 0x7fffu + ((u >> 16) & 1u)) >> 16;
}
__device__ __forceinline__ void split8v(const f32x4 a, const f32x4 b, ru4& hi, ru4& lo) {
#pragma unroll
  for (int j = 0; j < 4; j++) {
    const float x = (j < 2) ? a[2 * j] : b[2 * j - 4];
    const float y = (j < 2) ? a[2 * j + 1] : b[2 * j - 3];
    const unsigned hx = rne16(__float_as_uint(x)), hy = rne16(__float_as_uint(y));
    const float rx = x - __uint_as_float(hx << 16);
    const float ry = y - __uint_as_float(hy << 16);
    hi[j] = (hx & 0xffffu) | (hy << 16);
    lo[j] = (rne16(__float_as_uint(rx)) & 0xffffu) | (rne16(__float_as_uint(ry)) << 16);
  }
}

// ---------------------------------------------------------------------------
// Per-chunk MFMA compute: wave (wq,w1) does 16 rows x 64 gc via 4 gate-groups.
// A = W bf16 hi/lo from LDS (aligned 16B), B = h via 2x ds_read_b128 from the
// TRANSPOSED Ht[row][k] tile (r8 lesson: row-major-by-batch-row kills the
// 4-way l4-group bank conflict of the old Hs[k][row] scalar reads).
// D-layout (m89): col=lane&15 -> batch row l15; row=(lane>>4)*4+reg -> cg
// within 16-block = l4*4+reg  =>  u = ubase + g*4 + l4, gate = reg.
// ---------------------------------------------------------------------------
__device__ __forceinline__ void comp_mfma(SMT& sm, int wq, int w1, int l15, int l4,
                                          f32x4 acc[4])
{
  const int hr = w1 * 16 + l15;
  const f32x4 hv0 = *(const f32x4*)&sm.m.Ht[hr][l4 * 8];
  const f32x4 hv1 = *(const f32x4*)&sm.m.Ht[hr][l4 * 8 + 4];
  ru4 bhi, blo;
  split8v(hv0, hv1, bhi, blo);
  asm volatile("s_nop 1" : "+v"(bhi), "+v"(blo));   // VALU->MFMA RAW spacing
#pragma unroll
  for (int g = 0; g < 4; g++) {
    const int cr = wq * 64 + g * 16 + l15;
    ru4 ah = *(const ru4*)&sm.m.WsH[cr][l4 * 4];
    ru4 al = *(const ru4*)&sm.m.WsL[cr][l4 * 4];
    MFMA(acc[g], ah, bhi);
    MFMA(acc[g], ah, blo);
    MFMA(acc[g], al, bhi);
  }
}

// ---------------------------------------------------------------------------
// Software-pipelined gate-GEMM over NC 32-K chunks (NC divisible by 4).
// DEEPENED r7 pipeline: W prefetched 2 chunks ahead (4 named W4 slots),
// H (UC, latency-heavy) 3 ahead (4 named slot pairs). Unroll-by-4 loop body
// keeps every ring index STATIC (rule #20: no runtime-indexed reg arrays —
// and no r8-style mega-unroll that killed register allocation).
// vmcnt queue (position-verified): steady [W(c)4,H(c)2,W(c+1)4,H(c+1)2,H(c+2)2]
// = 14 outstanding; VMW(8) retires exactly W(c)+H(c). Prologue issues
// W0,H0,W1,H1,H2; each body then issues W(c+2),H(c+3). Junk tail prefetch
// stays inside ws; drained by the final vmcnt(0).
// POINTER CONVENTION (r0/r7): hb0/hb1 are ROW-BASE + lane-k-offset, no
// pre-offset; chunks k >= nc0 rebased via h1p = hb1 - nc0*32.
// ---------------------------------------------------------------------------
#define STW(wv) do { \
  *(ru4*)&sm.m.WsH[cgt][kt * 8]     = (wv).v[0]; \
  *(ru4*)&sm.m.WsH[cgt][kt * 8 + 4] = (wv).v[1]; \
  *(ru4*)&sm.m.WsL[cgt][kt * 8]     = (wv).v[2]; \
  *(ru4*)&sm.m.WsL[cgt][kt * 8 + 4] = (wv).v[3]; } while (0)
#define STH(a, b) do { \
  sm.m.Ht[r][p2 * 2]      = (a)[0]; sm.m.Ht[r][p2 * 2 + 1]  = (a)[1]; \
  sm.m.Ht[r][p2 * 2 + 16] = (b)[0]; sm.m.Ht[r][p2 * 2 + 17] = (b)[1]; } while (0)

__device__ void gemm_pipe(const u16* wbh, const u16* wbl,
                          const float* hb0, const float* hb1,
                          int NC, int nc0, f32x4 acc[4], SMT& sm,
                          int wq, int w1, int l15, int l4)
{
  const int tid = threadIdx.x;
  const int r = tid & 31, p2 = tid >> 5;          // H staging coords
  const int cgt = tid & 127, kt = tid >> 7;       // W staging coords
  const float* h1p = hb1 - (ull)nc0 * 32;
#define HBk(k) (((k) < nc0) ? (hb0 + (k) * 32) : (h1p + (k) * 32))
  W4 wr0, wr1, wr2, wr3;
  v2f h0a, h0b, h1a, h1b, h2a, h2b, h3a, h3b;
  ld_w4(wbh, wbl, wr0);
  ld_h(HBk(0), h0a, h0b);
  ld_w4(wbh + 32, wbl + 32, wr1);
  ld_h(HBk(1), h1a, h1b);
  ld_h(HBk(2), h2a, h2b);
  for (int c = 0; c < NC; c += 4) {
    // ---- body 0: chunk c ----
    VMW(8);
    STW(wr0); STH(h0a, h0b);
    __syncthreads();
    ld_w4(wbh + (c + 2) * 32, wbl + (c + 2) * 32, wr2);
    ld_h(HBk(c + 3), h3a, h3b);
    comp_mfma(sm, wq, w1, l15, l4, acc);
    __syncthreads();
    // ---- body 1: chunk c+1 ----
    VMW(8);
    STW(wr1); STH(h1a, h1b);
    __syncthreads();
    ld_w4(wbh + (c + 3) * 32, wbl + (c + 3) * 32, wr3);
    ld_h(HBk(c + 4), h0a, h0b);
    comp_mfma(sm, wq, w1, l15, l4, acc);
    __syncthreads();
    // ---- body 2: chunk c+2 ----
    VMW(8);
    STW(wr2); STH(h2a, h2b);
    __syncthreads();
    ld_w4(wbh + (c + 4) * 32, wbl + (c + 4) * 32, wr0);
    ld_h(HBk(c + 5), h1a, h1b);
    comp_mfma(sm, wq, w1, l15, l4, acc);
    __syncthreads();
    // ---- body 3: chunk c+3 ----
    VMW(8);
    STW(wr3); STH(h3a, h3b);
    __syncthreads();
    ld_w4(wbh + (c + 5) * 32, wbl + (c + 5) * 32, wr1);
    ld_h(HBk(c + 6), h2a, h2b);
    comp_mfma(sm, wq, w1, l15, l4, acc);
    __syncthreads();
  }
  asm volatile("s_waitcnt vmcnt(0)" ::: "memory");  // junk drained before reg reuse
  // MFMA->VALU RAW spacing before epilogue reads acc
  asm volatile("s_nop 7\n\ts_nop 7"
               : "+v"(acc[0]), "+v"(acc[1]), "+v"(acc[2]), "+v"(acc[3]));
#undef HBk
}

// ---- epilogue: lane owns (myrow, u = ubase+g*4+l4); gates = acc[g][0..3] ----
__device__ __forceinline__ void lstm_epi4(f32x4 acc[4], float cR[4], int row, int ubase, int l4,
                                          float* hout, __half* e16, int sstep)
{
#pragma unroll
  for (int g = 0; g < 4; g++) {
    const int u = ubase + g * 4 + l4;
    const float iv = sigf(acc[g][0]), fv = sigf(acc[g][1]);
    const float gv = tanhf(acc[g][2]), ov = sigf(acc[g][3]);
    const float cn = fv * cR[g] + iv * gv;
    cR[g] = cn;
    const float hn = ov * tanhf(cn);
    st1(hout + (ull)row * 256 + u, hn);
    if (e16) sth(e16 + ((ull)row * SS + sstep) * 256 + u, __float2half(hn));
  }
}

// ---- attention + fc for one batch row (UC transport) — r7 verbatim ----
__device__ void attn_fc(int row, int t, int slot, const float* h1r, const float* wdT,
                        const float* attn_b, const float* attn_v,
                        const __half* P16, const __half* E16,
                        const float* fc_w, const float* fc_b,
                        float* ctxb, float* out, SMT& sm)
{
  const int tid = threadIdx.x;
  __syncthreads();
  if (tid < 128) {
    float2 v = ld2(h1r + (ull)slot * BH + (ull)row * 256 + tid * 2);
    sm.at.h1s[tid * 2] = v.x; sm.at.h1s[tid * 2 + 1] = v.y;
  }
  __syncthreads();
  if (t >= 1 && tid < 64) {
    float a = 0.f;
#pragma unroll
    for (int j = 0; j < 4; j++) a += sm.at.h1s[tid + 64 * j] * fc_w[tid + 64 * j];
#pragma unroll
    for (int m = 32; m >= 1; m >>= 1) a += __shfl_xor(a, m, 64);
    if (tid == 0) {
      const float p = a + fc_b[0];
      out[(ull)row * TT + (t - 1)] = p;
      st1(ctxb + (ull)row * 288 + 256, p);
    }
  }
  if (t >= TT) return;
  float qv = attn_b[tid];
  for (int k = 0; k < 256; k += 4) {
    qv += sm.at.h1s[k]     * wdT[(ull)(k)     * 256 + tid];
    qv += sm.at.h1s[k + 1] * wdT[(ull)(k + 1) * 256 + tid];
    qv += sm.at.h1s[k + 2] * wdT[(ull)(k + 2) * 256 + tid];
    qv += sm.at.h1s[k + 3] * wdT[(ull)(k + 3) * 256 + tid];
  }
  sm.at.qs[tid] = qv;
  sm.at.vs[tid] = attn_v[tid];
  __syncthreads();
  const int wv = tid >> 6, lane = tid & 63;
  for (int s = wv; s < SS; s += 4) {
    const __half2* Pr = (const __half2*)(P16 + ((ull)row * SS + s) * 256);
    float a = 0.f;
#pragma unroll
    for (int jj = 0; jj < 2; jj++) {
      const int i2 = lane + 64 * jj;
      const float2 pv = __half22float2(Pr[i2]);
      const int g0 = i2 * 2;
      a += sm.at.vs[g0] * tanhf(pv.x + sm.at.qs[g0]);
      a += sm.at.vs[g0 + 1] * tanhf(pv.y + sm.at.qs[g0 + 1]);
    }
#pragma unroll
    for (int m = 32; m >= 1; m >>= 1) a += __shfl_xor(a, m, 64);
    if (lane == 0) sm.at.sc[s] = a;
  }
  __syncthreads();
  if (tid < 64) {
    float m = -1e30f;
    for (int i = tid; i < SS; i += 64) m = fmaxf(m, sm.at.sc[i]);
#pragma unroll
    for (int mm = 32; mm >= 1; mm >>= 1) m = fmaxf(m, __shfl_xor(m, mm, 64));
    if (tid == 0) sm.at.sred[0] = m;
  }
  __syncthreads();
  const float smax = sm.at.sred[0];
  if (tid < SS) sm.at.sc[tid] = expf(sm.at.sc[tid] - smax);
  __syncthreads();
  if (tid < 64) {
    float ssum = 0.f;
    for (int i = tid; i < SS; i += 64) ssum += sm.at.sc[i];
#pragma unroll
    for (int mm = 32; mm >= 1; mm >>= 1) ssum += __shfl_xor(ssum, mm, 64);
    if (tid == 0) sm.at.sred[1] = ssum;
  }
  __syncthreads();
  const float rinv = 1.f / sm.at.sred[1];
  const int u2 = tid & 127, sh = tid >> 7;
  float cx = 0.f, cy = 0.f;
  for (int s = sh * 84; s < sh * 84 + 84; s++) {
    const float w = sm.at.sc[s] * rinv;
    const float2 ev = __half22float2(*(const __half2*)(E16 + ((ull)row * SS + s) * 256 + u2 * 2));
    cx += w * ev.x; cy += w * ev.y;
  }
  sm.at.ctxs[sh * 256 + u2 * 2] = cx;
  sm.at.ctxs[sh * 256 + u2 * 2 + 1] = cy;
  __syncthreads();
  st1(ctxb + (ull)row * 288 + tid, sm.at.ctxs[tid] + sm.at.ctxs[256 + tid]);
}

// ---- enc_proj 64x64 gemm tile: P16 = E16 @ We^T — r7 verbatim ----
__device__ void proj_tile(const __half* E16, const float* attn_w, __half* P16,
                          int m0, int n0, SMT& sm)
{
  const int tid = threadIdx.x;
  const int mq = tid & 15, nq = tid >> 4;
  const int li = tid & 63, kq = tid >> 6;
  float acc[4][4] = {{0.f}};
  for (int k0 = 0; k0 < 256; k0 += 32) {
    float4 raw = *(const float4*)(E16 + (ull)(m0 + li) * 256 + k0 + kq * 8);
    const __half* hp = (const __half*)&raw;
#pragma unroll
    for (int i = 0; i < 8; i++) sm.g.As[kq * 8 + i][li] = __half2float(hp[i]);
    const float* gb = attn_w + (ull)(n0 + li) * 512 + k0 + kq * 8;
    const float4 v0 = *(const float4*)gb, v1 = *(const float4*)(gb + 4);
    sm.g.Bs[kq * 8 + 0][li] = v0.x; sm.g.Bs[kq * 8 + 1][li] = v0.y;
    sm.g.Bs[kq * 8 + 2][li] = v0.z; sm.g.Bs[kq * 8 + 3][li] = v0.w;
    sm.g.Bs[kq * 8 + 4][li] = v1.x; sm.g.Bs[kq * 8 + 5][li] = v1.y;
    sm.g.Bs[kq * 8 + 6][li] = v1.z; sm.g.Bs[kq * 8 + 7][li] = v1.w;
    __syncthreads();
#pragma unroll 8
    for (int kk = 0; kk < 32; kk++) {
      const float4 a4 = *(const float4*)&sm.g.As[kk][mq * 4];
      const float4 b4 = *(const float4*)&sm.g.Bs[kk][nq * 4];
      fma16(acc, a4, b4);
    }
    __syncthreads();
  }
#pragma unroll
  for (int i = 0; i < 4; i++) {
    const int m = m0 + mq * 4 + i;
#pragma unroll
    for (int j = 0; j < 2; j++) {
      __half2 h2; h2.x = __float2half(acc[i][j * 2]); h2.y = __float2half(acc[i][j * 2 + 1]);
      stu((unsigned*)(P16 + (ull)m * 256 + n0 + nq * 4) + j, *(unsigned*)&h2);
    }
  }
}

// ---------------------------------------------------------------------------
__global__ __launch_bounds__(256, 1) void seq2seq_pipe(
    const float* __restrict__ src,
    const float* __restrict__ attn_w, const float* __restrict__ attn_b,
    const float* __restrict__ attn_v,
    const float* __restrict__ fc_w, const float* __restrict__ fc_b,
    float* __restrict__ out, int* __restrict__ ib)
{
  __shared__ SMT sm;
  const int blk = blockIdx.x;
  const int tid = threadIdx.x;
  float* fb = (float*)ib + 65536;
  float* y0r  = fb + O_Y0;
  float* h1r  = fb + O_H1;
  float* h0r  = fb + O_H0;
  float* zb   = h0r + BH;          // zeroed by init; overwritten first at dec t=1
  float* ctxb = fb + O_CTX;
  const u16* whi0 = (const u16*)(fb + O_W0);
  const u16* wlo0 = whi0 + 1024ull * 320;
  const u16* whi1 = (const u16*)(fb + O_W1);
  const u16* wlo1 = whi1 + 1024ull * 512;
  const u16* dhi0 = whi1 + 2ull * 1024 * 512;
  const u16* dlo0 = whi1 + 3ull * 1024 * 512;
  const u16* dhi1 = whi1 + 4ull * 1024 * 512;
  const u16* dlo1 = whi1 + 5ull * 1024 * 512;
  const float* wp  = fb + O_WP;    // dec cell0 pred column [1024]
  const float* wdT = fb + O_WDT;
  const float* bp  = fb + O_BP;
  __half* E16 = (__half*)(fb + O_E16);
  __half* P16 = (__half*)(fb + O_P16);
  const int g = blk >> 5, m = blk & 31;
  const int rowg = g * 64;
  int* gf = ib + g * 1024;
  int* ife = gf;             // [0..168]
  int* ifa = gf + 704; int* ifh0 = gf + 736; int* ifh1 = gf + 768; int* ifp = gf + 900;

  // tile geometry: block = 32 rows x 128 gate-cols; wave = 16 rows x 64 gc
  const int lm = (m < 16) ? m : (m - 16);
  const int row0 = rowg + (lm & 1) * 32;
  const int gc0 = (lm >> 1) * 128;
  const int w = tid >> 6;
  const int l15 = tid & 15, l4 = (tid >> 4) & 3;
  const int wq = w >> 1, w1 = w & 1;
  const int gcw = gc0 + wq * 64;                // wave's 64 gate-cols
  const int myrow = row0 + w1 * 16 + l15;       // this lane's batch row
  const int ubase = gcw >> 2;                   // u = ubase + g*4 + l4
  const int r = tid & 31;                       // staging row
  const int cgt = tid & 127, kt = tid >> 7;     // W staging coords

  float cReg[4] = {0.f, 0.f, 0.f, 0.f};

  // ======== encoder: wavefront, single flag per iter (target 32) ========
  for (int t = 0; t <= SS; t++) {
    flag_wait2(t ? ife + (t - 1) : nullptr, 32, nullptr, 0);
    if (m < 16) {
      if (t < SS) {
        f32x4 acc[4];
#pragma unroll
        for (int gg = 0; gg < 4; gg++) {
          acc[gg] = *(const f32x4*)(bp + gcw + gg * 16 + l4 * 4);
          TOUCH(acc[gg]);
        }
        // ---- x chunk: W rows 0..31 (x wts + zero pad), Ht k-cols 16..31 zeroed ----
        {
          W4 wx;
          ld_w4(whi0 + (ull)(gc0 + cgt) * 320 + kt * 16,
                wlo0 + (ull)(gc0 + cgt) * 320 + kt * 16, wx);
          VMW(0);
          *(ru4*)&sm.m.WsH[cgt][kt * 8]     = wx.v[0];
          *(ru4*)&sm.m.WsH[cgt][kt * 8 + 4] = wx.v[1];
          *(ru4*)&sm.m.WsL[cgt][kt * 8]     = wx.v[2];
          *(ru4*)&sm.m.WsL[cgt][kt * 8 + 4] = wx.v[3];
          const int f = tid >> 5;
          sm.m.Ht[r][f]      = src[((ull)(row0 + r) * SS + t) * 16 + f];
          sm.m.Ht[r][f + 8]  = src[((ull)(row0 + r) * SS + t) * 16 + f + 8];
          sm.m.Ht[r][f + 16] = 0.f;
          sm.m.Ht[r][f + 24] = 0.f;
          __syncthreads();
          comp_mfma(sm, wq, w1, l15, l4, acc);
          __syncthreads();
        }
        // ---- h chunks: W rows 32.., h[0..255] ----
        const float* ysrc = (t == 0) ? zb : (y0r + (ull)((t + 1) & 1) * BH);
        const float* hb0 = ysrc + (ull)(row0 + r) * 256 + (tid >> 5) * 2;
        gemm_pipe(whi0 + (ull)(gc0 + cgt) * 320 + 32 + kt * 16,
                  wlo0 + (ull)(gc0 + cgt) * 320 + 32 + kt * 16,
                  hb0, hb0, 8, 8, acc, sm, wq, w1, l15, l4);
        lstm_epi4(acc, cReg, myrow, ubase, l4, y0r + (ull)(t & 1) * BH, nullptr, 0);
      }
    } else {
      if (t >= 1) {
        const int s = t - 1;
        f32x4 acc[4];
#pragma unroll
        for (int gg = 0; gg < 4; gg++) {
          acc[gg] = *(const f32x4*)(bp + 1024 + gcw + gg * 16 + l4 * 4);
          TOUCH(acc[gg]);
        }
        const float* ysrc = y0r + (ull)(s & 1) * BH;
        const float* hsrc = (s == 0) ? zb : (h1r + (ull)((s + 1) & 1) * BH);
        const float* hb0 = ysrc + (ull)(row0 + r) * 256 + (tid >> 5) * 2;
        const float* hb1 = hsrc + (ull)(row0 + r) * 256 + (tid >> 5) * 2;  // r0 convention: NO -256
        gemm_pipe(whi1 + (ull)(gc0 + cgt) * 512 + kt * 16,
                  wlo1 + (ull)(gc0 + cgt) * 512 + kt * 16,
                  hb0, hb1, 16, 8, acc, sm, wq, w1, l15, l4);
        lstm_epi4(acc, cReg, myrow, ubase, l4, h1r + (ull)(s & 1) * BH, E16, s);
      }
    }
    flag_arrive(ife + t);
  }

  // ======== enc_proj: group-local rows, 21 tiles per block ========
  if (tid == 0) poll(ife + SS, 32);
  __syncthreads();
  {
    const int em0 = rowg * SS;
    for (int tau = m; tau < 672; tau += 32)
      proj_tile(E16, attn_w, P16, em0 + (tau >> 2) * 64, (tau & 3) * 64, sm);
  }
  flag_arrive(ifp);

  // ======== decoder (cReg NOT reset: cell0/cell1 inherit enc-final c0e/c1e
  //          under the identical lane->(row,u) partition) ========
  for (int t = 0; t <= TT; t++) {
    if (t == 0) flag_wait2(ifp, 32, nullptr, 0);
    else flag_wait2(ifh1 + (t - 1), 16, nullptr, 0);
    const int slot = (t + 1) & 1;
    attn_fc(rowg + 2 * m,     t, slot, h1r, wdT, attn_b, attn_v, P16, E16, fc_w, fc_b, ctxb, out, sm);
    attn_fc(rowg + 2 * m + 1, t, slot, h1r, wdT, attn_b, attn_v, P16, E16, fc_w, fc_b, ctxb, out, sm);
    if (t == TT) break;
    flag_arrive(ifa + t);
    if (m < 16) {
      // ---- dec cell0: x = [ctx(256) | h0prev(256) | pred(1)] ----
      flag_wait2(ifa + t, 32, t ? ifh0 + (t - 1) : nullptr, 16);
      f32x4 acc[4];
#pragma unroll
      for (int gg = 0; gg < 4; gg++) {
        acc[gg] = *(const f32x4*)(bp + 2048 + gcw + gg * 16 + l4 * 4);
        TOUCH(acc[gg]);
      }
      const float* h0src = (t == 0) ? (y0r + BH) : (h0r + (ull)((t + 1) & 1) * BH);
      const float* hb0 = ctxb + (ull)(row0 + r) * 288 + (tid >> 5) * 2;
      const float* hb1 = h0src + (ull)(row0 + r) * 256 + (tid >> 5) * 2;  // r0 convention: NO -256
      gemm_pipe(dhi0 + (ull)(gc0 + cgt) * 512 + kt * 16,
                dlo0 + (ull)(gc0 + cgt) * 512 + kt * 16,
                hb0, hb1, 16, 8, acc, sm, wq, w1, l15, l4);
      const float p = ld1(ctxb + (ull)myrow * 288 + 256);
#pragma unroll
      for (int gg = 0; gg < 4; gg++) {
        const f32x4 wpv = *(const f32x4*)(wp + gcw + gg * 16 + l4 * 4);
        acc[gg] = acc[gg] + wpv * p;
      }
      lstm_epi4(acc, cReg, myrow, ubase, l4, h0r + (ull)(t & 1) * BH, nullptr, 0);
      flag_arrive(ifh0 + t);
    } else {
      // ---- dec cell1: x = [h0new(256) | h1prev(256)] ----
      flag_wait2(ifh0 + t, 16, t ? ifh1 + (t - 1) : nullptr, 16);
      f32x4 acc[4];
#pragma unroll
      for (int gg = 0; gg < 4; gg++) {
        acc[gg] = *(const f32x4*)(bp + 3072 + gcw + gg * 16 + l4 * 4);
        TOUCH(acc[gg]);
      }
      const float* hb0 = h0r + (ull)(t & 1) * BH + (ull)(row0 + r) * 256 + (tid >> 5) * 2;
      const float* hb1 = h1r + (ull)((t + 1) & 1) * BH + (ull)(row0 + r) * 256 + (tid >> 5) * 2;  // NO -256
      gemm_pipe(dhi1 + (ull)(gc0 + cgt) * 512 + kt * 16,
                dlo1 + (ull)(gc0 + cgt) * 512 + kt * 16,
                hb0, hb1, 16, 8, acc, sm, wq, w1, l15, l4);
      lstm_epi4(acc, cReg, myrow, ubase, l4, h1r + (ull)(t & 1) * BH, nullptr, 0);
      flag_arrive(ifh1 + t);
    }
  }
}

// ---------------------------------------------------------------------------
// Init: zero flags + zb, split weights (RNE) into bf16 hi/lo planes [cg][K]
// (cg = u*4+gate), pack biases, Wd^T, pred column, seed ctx pred col.
// layer0 KP=320: k<16 x | 16..31 zero | 32..287 h | 288..319 zero.
// ---------------------------------------------------------------------------
__device__ __forceinline__ void split_store(float v, u16* hi, u16* lo, ull i) {
  const unsigned u = __float_as_uint(v);
  const unsigned hb = (u + 0x7fffu + ((u >> 16) & 1u)) >> 16;
  const float rr = v - __uint_as_float(hb << 16);
  const unsigned ur = __float_as_uint(rr);
  const unsigned lb = (ur + 0x7fffu + ((ur >> 16) & 1u)) >> 16;
  hi[i] = (u16)hb; lo[i] = (u16)lb;
}

__global__ void init_all(
    const float* __restrict__ src,
    const float* __restrict__ ewih0, const float* __restrict__ ewhh0, const float* __restrict__ eb0,
    const float* __restrict__ ewih1, const float* __restrict__ ewhh1, const float* __restrict__ eb1,
    const float* __restrict__ dwih0, const float* __restrict__ dwhh0, const float* __restrict__ db0,
    const float* __restrict__ dwih1, const float* __restrict__ dwhh1, const float* __restrict__ db1,
    const float* __restrict__ attn_w, int* __restrict__ ib)
{
  const int gid = blockIdx.x * 256 + threadIdx.x;
  const int NG = 1024 * 256;
  float* fb = (float*)ib + 65536;
  u16* whi0 = (u16*)(fb + O_W0);
  u16* wlo0 = whi0 + 1024ull * 320;
  u16* whi1 = (u16*)(fb + O_W1);
  u16* wlo1 = whi1 + 1024ull * 512;
  u16* dhi0 = whi1 + 2ull * 1024 * 512;
  u16* dlo0 = whi1 + 3ull * 1024 * 512;
  u16* dhi1 = whi1 + 4ull * 1024 * 512;
  u16* dlo1 = whi1 + 5ull * 1024 * 512;
  float* wpd = fb + O_WP;

  for (int i = gid; i < 8192; i += NG) ib[i] = 0;
  for (int i = gid; i < (int)BH; i += NG) fb[O_H0 + BH + i] = 0.f;   // zb
  for (int i = gid; i < 1024 * 320; i += NG) {
    const int cg = i / 320, k = i - cg * 320, j = (cg & 3) * 256 + (cg >> 2);
    float v = 0.f;
    if (k < 16) v = ewih0[(ull)j * 16 + k];
    else if (k >= 32 && k < 288) v = ewhh0[(ull)j * 256 + (k - 32)];
    split_store(v, whi0, wlo0, i);
  }
  for (int i = gid; i < 1024 * 512; i += NG) {
    const int cg = i >> 9, k = i & 511, j = (cg & 3) * 256 + (cg >> 2);
    split_store((k < 256) ? ewih1[(ull)j * 256 + k] : ewhh1[(ull)j * 256 + k - 256], whi1, wlo1, i);
    split_store((k < 256) ? dwih0[(ull)j * 257 + 1 + k] : dwhh0[(ull)j * 256 + k - 256], dhi0, dlo0, i);
    split_store((k < 256) ? dwih1[(ull)j * 256 + k] : dwhh1[(ull)j * 256 + k - 256], dhi1, dlo1, i);
  }
  for (int i = gid; i < 1024; i += NG) {
    const int j = (i & 3) * 256 + (i >> 2);
    wpd[i] = dwih0[(ull)j * 257];
  }
  for (int i = gid; i < 256 * 256; i += NG) {
    const int k = i >> 8, gg = i & 255;
    fb[O_WDT + i] = attn_w[(ull)gg * 512 + 256 + k];
  }
  for (int i = gid; i < 4096; i += NG) {
    const int set = i >> 10, cg = i & 1023, j = (cg & 3) * 256 + (cg >> 2);
    const float* bsrc = (set == 0) ? eb0 : (set == 1) ? eb1 : (set == 2) ? db0 : db1;
    fb[O_BP + i] = bsrc[j];
  }
  for (int i = gid; i < 512; i += NG)
    fb[O_CTX + (ull)i * 288 + 256] = src[((ull)i * SS + 167) * 16 + 15];
}

extern "C" void kernel_launch(void* const* d_in, const int* in_sizes, int n_in,
                              void* d_out, int out_size, void* d_ws, size_t ws_size,
                              hipStream_t stream)
{
  const float* src    = (const float*)d_in[0];
  const float* ewih0  = (const float*)d_in[1];
  const float* ewhh0  = (const float*)d_in[2];
  const float* eb0    = (const float*)d_in[3];
  const float* ewih1  = (const float*)d_in[4];
  const float* ewhh1  = (const float*)d_in[5];
  const float* eb1    = (const float*)d_in[6];
  const float* dwih0  = (const float*)d_in[7];
  const float* dwhh0  = (const float*)d_in[8];
  const float* db0    = (const float*)d_in[9];
  const float* dwih1  = (const float*)d_in[10];
  const float* dwhh1  = (const float*)d_in[11];
  const float* db1    = (const float*)d_in[12];
  const float* attn_w = (const float*)d_in[13];
  const float* attn_b = (const float*)d_in[14];
  const float* attn_v = (const float*)d_in[15];
  // d_in[16] pos_bias: post-tanh, uniform over s -> softmax-invariant, unused.
  const float* fc_w   = (const float*)d_in[17];
  const float* fc_b   = (const float*)d_in[18];
  float* out = (float*)d_out;
  int* ib    = (int*)d_ws;

  init_all<<<1024, 256, 0, stream>>>(src, ewih0, ewhh0, eb0, ewih1, ewhh1, eb1,
                                     dwih0, dwhh0, db0, dwih1, dwhh1, db1, attn_w, ib);

  void* args[] = {
    (void*)&src, (void*)&attn_w, (void*)&attn_b, (void*)&attn_v,
    (void*)&fc_w, (void*)&fc_b, (void*)&out, (void*)&ib,
  };
  hipError_t lerr = hipLaunchCooperativeKernel((const void*)seq2seq_pipe, dim3(NBLK), dim3(NTHR),
                                               args, 0, stream);
  if (lerr != hipSuccess) {
    // flag/atomic sync only (no grid.sync); 1 block/CU resources + grid==CU count
    // guarantee co-residency under a plain launch as well.
    hipLaunchKernelGGL(seq2seq_pipe, dim3(NBLK), dim3(NTHR), 0, stream,
                       src, attn_w, attn_b, attn_v, fc_w, fc_b, out, ib);
  }
}

// Round 10
// 7028.999 us; speedup vs baseline: 1.1192x; 1.1192x over previous
//
#include <hip/hip_runtime.h>
#include <hip/hip_fp16.h>
#include <math.h>

#define BB 512
#define HH 256
#define SS 168
#define TT 24
#define NBLK 256
#define NTHR 512
typedef unsigned long long ull;
typedef unsigned short u16;
#define BH 131072ull  // 512*256

// ---- int area (from ws): per-group flags at ib + g*1024 ----
//   ife[0..168] tgt 32 | ifa 704+t tgt 32 | ifh0 736+t tgt 16 | ifh1 768+t tgt 16 | ifp 900 tgt 32
// ---- float offsets from fb = (float*)ws + 65536 ---- (r7/r9 map, unchanged)
#define O_Y0  0ull
#define O_H1  262144ull
#define O_H0  524288ull
#define O_CTX 786432ull   // 512 x 288 (cols 0..255 ctx, col 256 pred)
#define O_W0  933888ull   // whi0 [1024][320] bf16, wlo0 follows (163840 fl each)
#define O_W1  1261568ull  // bf16 planes [1024][512]: whi1,wlo1,dhi0,dlo0,dhi1,dlo1 (262144 fl each)
#define O_WP  2834432ull  // dec cell0 pred column [1024] f32
#define O_WDT 2835456ull  // Wd^T [256][256] f32
#define O_BP  2900992ull  // packed biases 4x1024 (e0,e1,d0,d1)
#define O_E16 2905088ull  // half[512][168][256]
#define O_P16 13915136ull // half[512][168][256]

typedef float f32x4 __attribute__((ext_vector_type(4)));
typedef float v2f __attribute__((ext_vector_type(2)));
typedef unsigned int ru4 __attribute__((ext_vector_type(4)));  // 8 bf16 raw (4 VGPR)

__device__ __forceinline__ float sigf(float x) { return 1.f / (1.f + expf(-x)); }

#define AR __ATOMIC_RELAXED
#define SCA __HIP_MEMORY_SCOPE_AGENT
__device__ __forceinline__ int aLd(int* p) { return __hip_atomic_load(p, AR, SCA); }
__device__ __forceinline__ int aAdd(int* p, int v) { return __hip_atomic_fetch_add(p, v, AR, SCA); }

// ---- UC transport: relaxed agent-scope (coherence-point) ops, no fences ----
__device__ __forceinline__ float2 ld2(const float* p) {
  ull raw = __hip_atomic_load((const ull*)p, AR, SCA);
  float2 v; v.x = __uint_as_float((unsigned)raw); v.y = __uint_as_float((unsigned)(raw >> 32));
  return v;
}
__device__ __forceinline__ float ld1(const float* p) {
  unsigned raw = __hip_atomic_load((const unsigned*)p, AR, SCA);
  return __uint_as_float(raw);
}
__device__ __forceinline__ void st1(float* p, float v) {
  __hip_atomic_store((unsigned*)p, __float_as_uint(v), AR, SCA);
}
__device__ __forceinline__ void sth(__half* p, __half v) {
  __hip_atomic_store((unsigned short*)p, __half_as_ushort(v), AR, SCA);
}
__device__ __forceinline__ void stu(unsigned* p, unsigned v) {
  __hip_atomic_store(p, v, AR, SCA);
}

// ---- manual-vmcnt loads (r0/r7-proven pattern: asm + "memory" clobber) ----
__device__ __forceinline__ void ld_h2(const float* p, v2f& a) {   // UC: 2 f32
  asm volatile("global_load_dwordx2 %0, %1, off sc0 sc1"
               : "=&v"(a) : "v"(p) : "memory");
}
__device__ __forceinline__ void ld_w2(const u16* ph, const u16* pl, ru4& h, ru4& l) {
  asm volatile("global_load_dwordx4 %0, %2, off\n\t"
               "global_load_dwordx4 %1, %3, off"
               : "=&v"(h), "=&v"(l) : "v"(ph), "v"(pl) : "memory");
}
#define VMW(n) asm volatile("s_waitcnt vmcnt(" #n ")" ::: "memory")

// inline-asm MFMA (r4/r6/r7-proven): D(=C) += A*B; VGPR C/D ok on gfx950.
#define MFMA(d, a, b) asm volatile("v_mfma_f32_16x16x32_bf16 %0, %1, %2, %0" \
                                   : "+v"(d) : "v"(a), "v"(b))
// force value materialization (compiler emits its waitcnt HERE, before our asm loads)
#define TOUCH(x) asm volatile("" : "+v"(x))

// ---- flag sync: no fences; data at coherence point before arrive ----
__device__ __forceinline__ void poll(int* f, int tgt) {
  while (aLd(f) < tgt) __builtin_amdgcn_s_sleep(1);
}
__device__ __forceinline__ void flag_arrive(int* f) {
  asm volatile("s_waitcnt vmcnt(0)" ::: "memory");
  __syncthreads();
  if (threadIdx.x == 0) aAdd(f, 1);
}
__device__ __forceinline__ void flag_wait2(int* f0, int t0, int* f1, int t1) {
  if (threadIdx.x == 0 && f0) poll(f0, t0);
  if (threadIdx.x == 64 && f1) poll(f1, t1);
  __syncthreads();
}

// ---- LDS ----
struct SMT {
  union {
    struct { unsigned WsH[128][20]; unsigned WsL[128][20]; float Ht[32][36]; } m;  // mfma gemm
    struct { float As[32][65];  float Bs[32][65]; } g;   // enc_proj gemm
    struct { float h1s[256], qs[256], vs[256], sc[192], ctxs[1024], sred[4]; } at;
  };
};

__device__ __forceinline__ void fma16(float acc[4][4], const float4 hv, const float4 wv) {
  acc[0][0] += hv.x * wv.x; acc[0][1] += hv.x * wv.y; acc[0][2] += hv.x * wv.z; acc[0][3] += hv.x * wv.w;
  acc[1][0] += hv.y * wv.x; acc[1][1] += hv.y * wv.y; acc[1][2] += hv.y * wv.z; acc[1][3] += hv.y * wv.w;
  acc[2][0] += hv.z * wv.x; acc[2][1] += hv.z * wv.y; acc[2][2] += hv.z * wv.z; acc[2][3] += hv.z * wv.w;
  acc[3][0] += hv.w * wv.x; acc[3][1] += hv.w * wv.y; acc[3][2] += hv.w * wv.z; acc[3][3] += hv.w * wv.w;
}

// ---- fp32 -> bf16 hi/lo split, RNE (unbiased; dropped lo*lo ~2^-18 relative) ----
__device__ __forceinline__ unsigned rne16(unsigned u) {
  return (u + 0x7fffu + ((u >> 16) & 1u)) >> 16;
}
__device__ __forceinline__ void split8v(const f32x4 a, const f32x4 b, ru4& hi, ru4& lo) {
#pragma unroll
  for (int j = 0; j < 4; j++) {
    const float x = (j < 2) ? a[2 * j] : b[2 * j - 4];
    const float y = (j < 2) ? a[2 * j + 1] : b[2 * j - 3];
    const unsigned hx = rne16(__float_as_uint(x)), hy = rne16(__float_as_uint(y));
    const float rx = x - __uint_as_float(hx << 16);
    const float ry = y - __uint_as_float(hy << 16);
    hi[j] = (hx & 0xffffu) | (hy << 16);
    lo[j] = (rne16(__float_as_uint(rx)) & 0xffffu) | (rne16(__float_as_uint(ry)) << 16);
  }
}

// ---------------------------------------------------------------------------
// Per-chunk MFMA compute, 8-wave block: wave w = (w1 = w&1 row-half,
// wq = w>>1 gc-quarter) does 16 rows x 32 gc via 2 gate-groups. 6 MFMAs.
// A = W bf16 hi/lo from LDS, B = h from Ht[row][k] split in-reg.
// D-layout (m89, r7-validated): batch row = l15; u = ubase + g*4 + l4,
// gate = reg.
// ---------------------------------------------------------------------------
__device__ __forceinline__ void comp_mfma(SMT& sm, int wq, int w1, int l15, int l4,
                                          f32x4 acc[2])
{
  const int hr = w1 * 16 + l15;
  const f32x4 hv0 = *(const f32x4*)&sm.m.Ht[hr][l4 * 8];
  const f32x4 hv1 = *(const f32x4*)&sm.m.Ht[hr][l4 * 8 + 4];
  ru4 bhi, blo;
  split8v(hv0, hv1, bhi, blo);
  asm volatile("s_nop 1" : "+v"(bhi), "+v"(blo));   // VALU->MFMA RAW spacing
#pragma unroll
  for (int g = 0; g < 2; g++) {
    const int cr = wq * 32 + g * 16 + l15;
    ru4 ah = *(const ru4*)&sm.m.WsH[cr][l4 * 4];
    ru4 al = *(const ru4*)&sm.m.WsL[cr][l4 * 4];
    MFMA(acc[g], ah, bhi);
    MFMA(acc[g], ah, blo);
    MFMA(acc[g], al, bhi);
  }
}

// ---------------------------------------------------------------------------
// Software-pipelined gate-GEMM over NC 32-K chunks (NC divisible by 4),
// 512-thread staging: W = 2 dwordx4/thread (cgt = tid&127, kt = tid>>7 in
// 0..3, 8 u16 each of hi+lo planes); H = 1 dwordx2/thread (r = tid&31,
// p2 = tid>>5 in 0..15 -> k pair p2*2). 3 loads issued per chunk.
// Pipeline: W 2 chunks ahead, H 3 ahead, 4-slot static rings; steady
// outstanding before wait = 7, VMW(4) retires exactly W(c)+H(c)
// (position-verified incl. prologue). Junk tail prefetch stays inside ws;
// drained by the final vmcnt(0).
// POINTER CONVENTION (r0/r7): hb0/hb1 are ROW-BASE + lane-k-offset, no
// pre-offset; chunks k >= nc0 rebased via h1p = hb1 - nc0*32.
// ---------------------------------------------------------------------------
#define STW(wh, wl) do { \
  *(ru4*)&sm.m.WsH[cgt][kt * 4] = (wh); \
  *(ru4*)&sm.m.WsL[cgt][kt * 4] = (wl); } while (0)
#define STH(a) do { \
  sm.m.Ht[r][p2 * 2] = (a)[0]; sm.m.Ht[r][p2 * 2 + 1] = (a)[1]; } while (0)

__device__ void gemm_pipe(const u16* wbh, const u16* wbl,
                          const float* hb0, const float* hb1,
                          int NC, int nc0, f32x4 acc[2], SMT& sm,
                          int wq, int w1, int l15, int l4)
{
  const int tid = threadIdx.x;
  const int r = tid & 31, p2 = tid >> 5;          // H staging coords (p2 0..15)
  const int cgt = tid & 127, kt = tid >> 7;       // W staging coords (kt 0..3)
  const float* h1p = hb1 - (ull)nc0 * 32;
#define HBk(k) (((k) < nc0) ? (hb0 + (k) * 32) : (h1p + (k) * 32))
  ru4 wh0, wl0, wh1, wl1, wh2, wl2, wh3, wl3;
  v2f h0, h1, h2, h3;
  ld_w2(wbh,      wbl,      wh0, wl0);
  ld_h2(HBk(0), h0);
  ld_w2(wbh + 32, wbl + 32, wh1, wl1);
  ld_h2(HBk(1), h1);
  ld_h2(HBk(2), h2);
  for (int c = 0; c < NC; c += 4) {
    // ---- body 0: chunk c ----
    VMW(4);
    STW(wh0, wl0); STH(h0);
    __syncthreads();
    ld_w2(wbh + (c + 2) * 32, wbl + (c + 2) * 32, wh2, wl2);
    ld_h2(HBk(c + 3), h3);
    comp_mfma(sm, wq, w1, l15, l4, acc);
    __syncthreads();
    // ---- body 1: chunk c+1 ----
    VMW(4);
    STW(wh1, wl1); STH(h1);
    __syncthreads();
    ld_w2(wbh + (c + 3) * 32, wbl + (c + 3) * 32, wh3, wl3);
    ld_h2(HBk(c + 4), h0);
    comp_mfma(sm, wq, w1, l15, l4, acc);
    __syncthreads();
    // ---- body 2: chunk c+2 ----
    VMW(4);
    STW(wh2, wl2); STH(h2);
    __syncthreads();
    ld_w2(wbh + (c + 4) * 32, wbl + (c + 4) * 32, wh0, wl0);
    ld_h2(HBk(c + 5), h1);
    comp_mfma(sm, wq, w1, l15, l4, acc);
    __syncthreads();
    // ---- body 3: chunk c+3 ----
    VMW(4);
    STW(wh3, wl3); STH(h3);
    __syncthreads();
    ld_w2(wbh + (c + 5) * 32, wbl + (c + 5) * 32, wh1, wl1);
    ld_h2(HBk(c + 6), h2);
    comp_mfma(sm, wq, w1, l15, l4, acc);
    __syncthreads();
  }
  asm volatile("s_waitcnt vmcnt(0)" ::: "memory");  // junk drained before reg reuse
  // MFMA->VALU RAW spacing before epilogue reads acc
  asm volatile("s_nop 7\n\ts_nop 7" : "+v"(acc[0]), "+v"(acc[1]));
#undef HBk
}

// ---- epilogue: lane owns (myrow, u = ubase+g*4+l4), g<2; gates = acc[g][0..3] ----
__device__ __forceinline__ void lstm_epi2(f32x4 acc[2], float cR[2], int row, int ubase, int l4,
                                          float* hout, __half* e16, int sstep)
{
#pragma unroll
  for (int g = 0; g < 2; g++) {
    const int u = ubase + g * 4 + l4;
    const float iv = sigf(acc[g][0]), fv = sigf(acc[g][1]);
    const float gv = tanhf(acc[g][2]), ov = sigf(acc[g][3]);
    const float cn = fv * cR[g] + iv * gv;
    cR[g] = cn;
    const float hn = ov * tanhf(cn);
    st1(hout + (ull)row * 256 + u, hn);
    if (e16) sth(e16 + ((ull)row * SS + sstep) * 256 + u, __float2half(hn));
  }
}

// ---- attention + fc for one batch row (UC transport), 512-thread version ----
__device__ void attn_fc(int row, int t, int slot, const float* h1r, const float* wdT,
                        const float* attn_b, const float* attn_v,
                        const __half* P16, const __half* E16,
                        const float* fc_w, const float* fc_b,
                        float* ctxb, float* out, SMT& sm)
{
  const int tid = threadIdx.x;
  __syncthreads();
  if (tid < 128) {
    float2 v = ld2(h1r + (ull)slot * BH + (ull)row * 256 + tid * 2);
    sm.at.h1s[tid * 2] = v.x; sm.at.h1s[tid * 2 + 1] = v.y;
  }
  __syncthreads();
  if (t >= 1 && tid < 64) {
    float a = 0.f;
#pragma unroll
    for (int j = 0; j < 4; j++) a += sm.at.h1s[tid + 64 * j] * fc_w[tid + 64 * j];
#pragma unroll
    for (int m = 32; m >= 1; m >>= 1) a += __shfl_xor(a, m, 64);
    if (tid == 0) {
      const float p = a + fc_b[0];
      out[(ull)row * TT + (t - 1)] = p;
      st1(ctxb + (ull)row * 288 + 256, p);
    }
  }
  if (t >= TT) return;
  if (tid < 256) {
    float qv = attn_b[tid];
    for (int k = 0; k < 256; k += 4) {
      qv += sm.at.h1s[k]     * wdT[(ull)(k)     * 256 + tid];
      qv += sm.at.h1s[k + 1] * wdT[(ull)(k + 1) * 256 + tid];
      qv += sm.at.h1s[k + 2] * wdT[(ull)(k + 2) * 256 + tid];
      qv += sm.at.h1s[k + 3] * wdT[(ull)(k + 3) * 256 + tid];
    }
    sm.at.qs[tid] = qv;
    sm.at.vs[tid] = attn_v[tid];
  }
  __syncthreads();
  const int wv = tid >> 6, lane = tid & 63;
  for (int s = wv; s < SS; s += 8) {
    const __half2* Pr = (const __half2*)(P16 + ((ull)row * SS + s) * 256);
    float a = 0.f;
#pragma unroll
    for (int jj = 0; jj < 2; jj++) {
      const int i2 = lane + 64 * jj;
      const float2 pv = __half22float2(Pr[i2]);
      const int g0 = i2 * 2;
      a += sm.at.vs[g0] * tanhf(pv.x + sm.at.qs[g0]);
      a += sm.at.vs[g0 + 1] * tanhf(pv.y + sm.at.qs[g0 + 1]);
    }
#pragma unroll
    for (int m = 32; m >= 1; m >>= 1) a += __shfl_xor(a, m, 64);
    if (lane == 0) sm.at.sc[s] = a;
  }
  __syncthreads();
  if (tid < 64) {
    float m = -1e30f;
    for (int i = tid; i < SS; i += 64) m = fmaxf(m, sm.at.sc[i]);
#pragma unroll
    for (int mm = 32; mm >= 1; mm >>= 1) m = fmaxf(m, __shfl_xor(m, mm, 64));
    if (tid == 0) sm.at.sred[0] = m;
  }
  __syncthreads();
  const float smax = sm.at.sred[0];
  if (tid < SS) sm.at.sc[tid] = expf(sm.at.sc[tid] - smax);
  __syncthreads();
  if (tid < 64) {
    float ssum = 0.f;
    for (int i = tid; i < SS; i += 64) ssum += sm.at.sc[i];
#pragma unroll
    for (int mm = 32; mm >= 1; mm >>= 1) ssum += __shfl_xor(ssum, mm, 64);
    if (tid == 0) sm.at.sred[1] = ssum;
  }
  __syncthreads();
  const float rinv = 1.f / sm.at.sred[1];
  const int u2 = tid & 127, sh = tid >> 7;   // sh 0..3, 42 s each
  float cx = 0.f, cy = 0.f;
  for (int s = sh * 42; s < sh * 42 + 42; s++) {
    const float w = sm.at.sc[s] * rinv;
    const float2 ev = __half22float2(*(const __half2*)(E16 + ((ull)row * SS + s) * 256 + u2 * 2));
    cx += w * ev.x; cy += w * ev.y;
  }
  sm.at.ctxs[sh * 256 + u2 * 2] = cx;
  sm.at.ctxs[sh * 256 + u2 * 2 + 1] = cy;
  __syncthreads();
  if (tid < 256)
    st1(ctxb + (ull)row * 288 + tid,
        sm.at.ctxs[tid] + sm.at.ctxs[256 + tid] + sm.at.ctxs[512 + tid] + sm.at.ctxs[768 + tid]);
}

// ---- enc_proj 64x64 gemm tile (lower 256 threads active; upper barrier-only) ----
__device__ void proj_tile(const __half* E16, const float* attn_w, __half* P16,
                          int m0, int n0, SMT& sm)
{
  const int tid = threadIdx.x;
  const bool act = tid < 256;
  const int mq = tid & 15, nq = (tid >> 4) & 15;
  const int li = tid & 63, kq = (tid >> 6) & 3;
  float acc[4][4] = {{0.f}};
  for (int k0 = 0; k0 < 256; k0 += 32) {
    if (act) {
      float4 raw = *(const float4*)(E16 + (ull)(m0 + li) * 256 + k0 + kq * 8);
      const __half* hp = (const __half*)&raw;
#pragma unroll
      for (int i = 0; i < 8; i++) sm.g.As[kq * 8 + i][li] = __half2float(hp[i]);
      const float* gb = attn_w + (ull)(n0 + li) * 512 + k0 + kq * 8;
      const float4 v0 = *(const float4*)gb, v1 = *(const float4*)(gb + 4);
      sm.g.Bs[kq * 8 + 0][li] = v0.x; sm.g.Bs[kq * 8 + 1][li] = v0.y;
      sm.g.Bs[kq * 8 + 2][li] = v0.z; sm.g.Bs[kq * 8 + 3][li] = v0.w;
      sm.g.Bs[kq * 8 + 4][li] = v1.x; sm.g.Bs[kq * 8 + 5][li] = v1.y;
      sm.g.Bs[kq * 8 + 6][li] = v1.z; sm.g.Bs[kq * 8 + 7][li] = v1.w;
    }
    __syncthreads();
    if (act) {
#pragma unroll 8
      for (int kk = 0; kk < 32; kk++) {
        const float4 a4 = *(const float4*)&sm.g.As[kk][mq * 4];
        const float4 b4 = *(const float4*)&sm.g.Bs[kk][nq * 4];
        fma16(acc, a4, b4);
      }
    }
    __syncthreads();
  }
  if (act) {
#pragma unroll
    for (int i = 0; i < 4; i++) {
      const int m = m0 + mq * 4 + i;
#pragma unroll
      for (int j = 0; j < 2; j++) {
        __half2 h2; h2.x = __float2half(acc[i][j * 2]); h2.y = __float2half(acc[i][j * 2 + 1]);
        stu((unsigned*)(P16 + (ull)m * 256 + n0 + nq * 4) + j, *(unsigned*)&h2);
      }
    }
  }
}

// ---------------------------------------------------------------------------
__global__ __launch_bounds__(512, 1) void seq2seq_pipe(
    const float* __restrict__ src,
    const float* __restrict__ attn_w, const float* __restrict__ attn_b,
    const float* __restrict__ attn_v,
    const float* __restrict__ fc_w, const float* __restrict__ fc_b,
    float* __restrict__ out, int* __restrict__ ib)
{
  __shared__ SMT sm;
  const int blk = blockIdx.x;
  const int tid = threadIdx.x;
  float* fb = (float*)ib + 65536;
  float* y0r  = fb + O_Y0;
  float* h1r  = fb + O_H1;
  float* h0r  = fb + O_H0;
  float* zb   = h0r + BH;          // zeroed by init; overwritten first at dec t=1
  float* ctxb = fb + O_CTX;
  const u16* whi0 = (const u16*)(fb + O_W0);
  const u16* wlo0 = whi0 + 1024ull * 320;
  const u16* whi1 = (const u16*)(fb + O_W1);
  const u16* wlo1 = whi1 + 1024ull * 512;
  const u16* dhi0 = whi1 + 2ull * 1024 * 512;
  const u16* dlo0 = whi1 + 3ull * 1024 * 512;
  const u16* dhi1 = whi1 + 4ull * 1024 * 512;
  const u16* dlo1 = whi1 + 5ull * 1024 * 512;
  const float* wp  = fb + O_WP;    // dec cell0 pred column [1024]
  const float* wdT = fb + O_WDT;
  const float* bp  = fb + O_BP;
  __half* E16 = (__half*)(fb + O_E16);
  __half* P16 = (__half*)(fb + O_P16);
  const int g = blk >> 5, m = blk & 31;
  const int rowg = g * 64;
  int* gf = ib + g * 1024;
  int* ife = gf;             // [0..168]
  int* ifa = gf + 704; int* ifh0 = gf + 736; int* ifh1 = gf + 768; int* ifp = gf + 900;

  // tile geometry: block = 32 rows x 128 gate-cols; 8 waves: 16 rows x 32 gc
  const int lm = (m < 16) ? m : (m - 16);
  const int row0 = rowg + (lm & 1) * 32;
  const int gc0 = (lm >> 1) * 128;
  const int w = tid >> 6;
  const int l15 = tid & 15, l4 = (tid >> 4) & 3;
  const int w1 = w & 1, wq = w >> 1;            // row-half, gc-quarter
  const int gcw = gc0 + wq * 32;                // wave's 32 gate-cols
  const int myrow = row0 + w1 * 16 + l15;       // this lane's batch row
  const int ubase = gcw >> 2;                   // u = ubase + g*4 + l4
  const int r = tid & 31;                       // staging row
  const int cgt = tid & 127, kt = tid >> 7;     // W staging coords (kt 0..3)

  float cReg[2] = {0.f, 0.f};

  // ======== encoder: wavefront, single flag per iter (target 32) ========
  for (int t = 0; t <= SS; t++) {
    flag_wait2(t ? ife + (t - 1) : nullptr, 32, nullptr, 0);
    if (m < 16) {
      if (t < SS) {
        f32x4 acc[2];
#pragma unroll
        for (int gg = 0; gg < 2; gg++) {
          acc[gg] = *(const f32x4*)(bp + gcw + gg * 16 + l4 * 4);
          TOUCH(acc[gg]);
        }
        // ---- x chunk: W k 0..31 (x wts + zero pad), Ht cols 16..31 zeroed ----
        {
          ru4 wxh, wxl;
          ld_w2(whi0 + (ull)(gc0 + cgt) * 320 + kt * 8,
                wlo0 + (ull)(gc0 + cgt) * 320 + kt * 8, wxh, wxl);
          VMW(0);
          *(ru4*)&sm.m.WsH[cgt][kt * 4] = wxh;
          *(ru4*)&sm.m.WsL[cgt][kt * 4] = wxl;
          const int f = tid >> 5;   // 0..15
          sm.m.Ht[r][f]      = src[((ull)(row0 + r) * SS + t) * 16 + f];
          sm.m.Ht[r][f + 16] = 0.f;
          __syncthreads();
          comp_mfma(sm, wq, w1, l15, l4, acc);
          __syncthreads();
        }
        // ---- h chunks: W k 32.., h[0..255] ----
        const float* ysrc = (t == 0) ? zb : (y0r + (ull)((t + 1) & 1) * BH);
        const float* hb0 = ysrc + (ull)(row0 + r) * 256 + (tid >> 5) * 2;
        gemm_pipe(whi0 + (ull)(gc0 + cgt) * 320 + 32 + kt * 8,
                  wlo0 + (ull)(gc0 + cgt) * 320 + 32 + kt * 8,
                  hb0, hb0, 8, 8, acc, sm, wq, w1, l15, l4);
        lstm_epi2(acc, cReg, myrow, ubase, l4, y0r + (ull)(t & 1) * BH, nullptr, 0);
      }
    } else {
      if (t >= 1) {
        const int s = t - 1;
        f32x4 acc[2];
#pragma unroll
        for (int gg = 0; gg < 2; gg++) {
          acc[gg] = *(const f32x4*)(bp + 1024 + gcw + gg * 16 + l4 * 4);
          TOUCH(acc[gg]);
        }
        const float* ysrc = y0r + (ull)(s & 1) * BH;
        const float* hsrc = (s == 0) ? zb : (h1r + (ull)((s + 1) & 1) * BH);
        const float* hb0 = ysrc + (ull)(row0 + r) * 256 + (tid >> 5) * 2;
        const float* hb1 = hsrc + (ull)(row0 + r) * 256 + (tid >> 5) * 2;  // r0 convention: NO pre-offset
        gemm_pipe(whi1 + (ull)(gc0 + cgt) * 512 + kt * 8,
                  wlo1 + (ull)(gc0 + cgt) * 512 + kt * 8,
                  hb0, hb1, 16, 8, acc, sm, wq, w1, l15, l4);
        lstm_epi2(acc, cReg, myrow, ubase, l4, h1r + (ull)(s & 1) * BH, E16, s);
      }
    }
    flag_arrive(ife + t);
  }

  // ======== enc_proj: group-local rows, 21 tiles per block ========
  if (tid == 0) poll(ife + SS, 32);
  __syncthreads();
  {
    const int em0 = rowg * SS;
    for (int tau = m; tau < 672; tau += 32)
      proj_tile(E16, attn_w, P16, em0 + (tau >> 2) * 64, (tau & 3) * 64, sm);
  }
  flag_arrive(ifp);

  // ======== decoder (cReg NOT reset: cell0/cell1 inherit enc-final c0e/c1e
  //          under the identical lane->(row,u) partition) ========
  for (int t = 0; t <= TT; t++) {
    if (t == 0) flag_wait2(ifp, 32, nullptr, 0);
    else flag_wait2(ifh1 + (t - 1), 16, nullptr, 0);
    const int slot = (t + 1) & 1;
    attn_fc(rowg + 2 * m,     t, slot, h1r, wdT, attn_b, attn_v, P16, E16, fc_w, fc_b, ctxb, out, sm);
    attn_fc(rowg + 2 * m + 1, t, slot, h1r, wdT, attn_b, attn_v, P16, E16, fc_w, fc_b, ctxb, out, sm);
    if (t == TT) break;
    flag_arrive(ifa + t);
    if (m < 16) {
      // ---- dec cell0: x = [ctx(256) | h0prev(256) | pred(1)] ----
      flag_wait2(ifa + t, 32, t ? ifh0 + (t - 1) : nullptr, 16);
      f32x4 acc[2];
#pragma unroll
      for (int gg = 0; gg < 2; gg++) {
        acc[gg] = *(const f32x4*)(bp + 2048 + gcw + gg * 16 + l4 * 4);
        TOUCH(acc[gg]);
      }
      const float* h0src = (t == 0) ? (y0r + BH) : (h0r + (ull)((t + 1) & 1) * BH);
      const float* hb0 = ctxb + (ull)(row0 + r) * 288 + (tid >> 5) * 2;
      const float* hb1 = h0src + (ull)(row0 + r) * 256 + (tid >> 5) * 2;  // NO pre-offset
      gemm_pipe(dhi0 + (ull)(gc0 + cgt) * 512 + kt * 8,
                dlo0 + (ull)(gc0 + cgt) * 512 + kt * 8,
                hb0, hb1, 16, 8, acc, sm, wq, w1, l15, l4);
      const float p = ld1(ctxb + (ull)myrow * 288 + 256);
#pragma unroll
      for (int gg = 0; gg < 2; gg++) {
        const f32x4 wpv = *(const f32x4*)(wp + gcw + gg * 16 + l4 * 4);
        acc[gg] = acc[gg] + wpv * p;
      }
      lstm_epi2(acc, cReg, myrow, ubase, l4, h0r + (ull)(t & 1) * BH, nullptr, 0);
      flag_arrive(ifh0 + t);
    } else {
      // ---- dec cell1: x = [h0new(256) | h1prev(256)] ----
      flag_wait2(ifh0 + t, 16, t ? ifh1 + (t - 1) : nullptr, 16);
      f32x4 acc[2];
#pragma unroll
      for (int gg = 0; gg < 2; gg++) {
        acc[gg] = *(const f32x4*)(bp + 3072 + gcw + gg * 16 + l4 * 4);
        TOUCH(acc[gg]);
      }
      const float* hb0 = h0r + (ull)(t & 1) * BH + (ull)(row0 + r) * 256 + (tid >> 5) * 2;
      const float* hb1 = h1r + (ull)((t + 1) & 1) * BH + (ull)(row0 + r) * 256 + (tid >> 5) * 2;  // NO pre-offset
      gemm_pipe(dhi1 + (ull)(gc0 + cgt) * 512 + kt * 8,
                dlo1 + (ull)(gc0 + cgt) * 512 + kt * 8,
                hb0, hb1, 16, 8, acc, sm, wq, w1, l15, l4);
      lstm_epi2(acc, cReg, myrow, ubase, l4, h1r + (ull)(t & 1) * BH, nullptr, 0);
      flag_arrive(ifh1 + t);
    }
  }
}

// ---------------------------------------------------------------------------
// Init: zero flags + zb, split weights (RNE) into bf16 hi/lo planes [cg][K]
// (cg = u*4+gate), pack biases, Wd^T, pred column, seed ctx pred col.
// layer0 KP=320: k<16 x | 16..31 zero | 32..287 h | 288..319 zero.
// ---------------------------------------------------------------------------
__device__ __forceinline__ void split_store(float v, u16* hi, u16* lo, ull i) {
  const unsigned u = __float_as_uint(v);
  const unsigned hb = (u + 0x7fffu + ((u >> 16) & 1u)) >> 16;
  const float rr = v - __uint_as_float(hb << 16);
  const unsigned ur = __float_as_uint(rr);
  const unsigned lb = (ur + 0x7fffu + ((ur >> 16) & 1u)) >> 16;
  hi[i] = (u16)hb; lo[i] = (u16)lb;
}

__global__ void init_all(
    const float* __restrict__ src,
    const float* __restrict__ ewih0, const float* __restrict__ ewhh0, const float* __restrict__ eb0,
    const float* __restrict__ ewih1, const float* __restrict__ ewhh1, const float* __restrict__ eb1,
    const float* __restrict__ dwih0, const float* __restrict__ dwhh0, const float* __restrict__ db0,
    const float* __restrict__ dwih1, const float* __restrict__ dwhh1, const float* __restrict__ db1,
    const float* __restrict__ attn_w, int* __restrict__ ib)
{
  const int gid = blockIdx.x * 256 + threadIdx.x;
  const int NG = 1024 * 256;
  float* fb = (float*)ib + 65536;
  u16* whi0 = (u16*)(fb + O_W0);
  u16* wlo0 = whi0 + 1024ull * 320;
  u16* whi1 = (u16*)(fb + O_W1);
  u16* wlo1 = whi1 + 1024ull * 512;
  u16* dhi0 = whi1 + 2ull * 1024 * 512;
  u16* dlo0 = whi1 + 3ull * 1024 * 512;
  u16* dhi1 = whi1 + 4ull * 1024 * 512;
  u16* dlo1 = whi1 + 5ull * 1024 * 512;
  float* wpd = fb + O_WP;

  for (int i = gid; i < 8192; i += NG) ib[i] = 0;
  for (int i = gid; i < (int)BH; i += NG) fb[O_H0 + BH + i] = 0.f;   // zb
  for (int i = gid; i < 1024 * 320; i += NG) {
    const int cg = i / 320, k = i - cg * 320, j = (cg & 3) * 256 + (cg >> 2);
    float v = 0.f;
    if (k < 16) v = ewih0[(ull)j * 16 + k];
    else if (k >= 32 && k < 288) v = ewhh0[(ull)j * 256 + (k - 32)];
    split_store(v, whi0, wlo0, i);
  }
  for (int i = gid; i < 1024 * 512; i += NG) {
    const int cg = i >> 9, k = i & 511, j = (cg & 3) * 256 + (cg >> 2);
    split_store((k < 256) ? ewih1[(ull)j * 256 + k] : ewhh1[(ull)j * 256 + k - 256], whi1, wlo1, i);
    split_store((k < 256) ? dwih0[(ull)j * 257 + 1 + k] : dwhh0[(ull)j * 256 + k - 256], dhi0, dlo0, i);
    split_store((k < 256) ? dwih1[(ull)j * 256 + k] : dwhh1[(ull)j * 256 + k - 256], dhi1, dlo1, i);
  }
  for (int i = gid; i < 1024; i += NG) {
    const int j = (i & 3) * 256 + (i >> 2);
    wpd[i] = dwih0[(ull)j * 257];
  }
  for (int i = gid; i < 256 * 256; i += NG) {
    const int k = i >> 8, gg = i & 255;
    fb[O_WDT + i] = attn_w[(ull)gg * 512 + 256 + k];
  }
  for (int i = gid; i < 4096; i += NG) {
    const int set = i >> 10, cg = i & 1023, j = (cg & 3) * 256 + (cg >> 2);
    const float* bsrc = (set == 0) ? eb0 : (set == 1) ? eb1 : (set == 2) ? db0 : db1;
    fb[O_BP + i] = bsrc[j];
  }
  for (int i = gid; i < 512; i += NG)
    fb[O_CTX + (ull)i * 288 + 256] = src[((ull)i * SS + 167) * 16 + 15];
}

extern "C" void kernel_launch(void* const* d_in, const int* in_sizes, int n_in,
                              void* d_out, int out_size, void* d_ws, size_t ws_size,
                              hipStream_t stream)
{
  const float* src    = (const float*)d_in[0];
  const float* ewih0  = (const float*)d_in[1];
  const float* ewhh0  = (const float*)d_in[2];
  const float* eb0    = (const float*)d_in[3];
  const float* ewih1  = (const float*)d_in[4];
  const float* ewhh1  = (const float*)d_in[5];
  const float* eb1    = (const float*)d_in[6];
  const float* dwih0  = (const float*)d_in[7];
  const float* dwhh0  = (const float*)d_in[8];
  const float* db0    = (const float*)d_in[9];
  const float* dwih1  = (const float*)d_in[10];
  const float* dwhh1  = (const float*)d_in[11];
  const float* db1    = (const float*)d_in[12];
  const float* attn_w = (const float*)d_in[13];
  const float* attn_b = (const float*)d_in[14];
  const float* attn_v = (const float*)d_in[15];
  // d_in[16] pos_bias: post-tanh, uniform over s -> softmax-invariant, unused.
  const float* fc_w   = (const float*)d_in[17];
  const float* fc_b   = (const float*)d_in[18];
  float* out = (float*)d_out;
  int* ib    = (int*)d_ws;

  init_all<<<1024, 256, 0, stream>>>(src, ewih0, ewhh0, eb0, ewih1, ewhh1, eb1,
                                     dwih0, dwhh0, db0, dwih1, dwhh1, db1, attn_w, ib);

  void* args[] = {
    (void*)&src, (void*)&attn_w, (void*)&attn_b, (void*)&attn_v,
    (void*)&fc_w, (void*)&fc_b, (void*)&out, (void*)&ib,
  };
  hipError_t lerr = hipLaunchCooperativeKernel((const void*)seq2seq_pipe, dim3(NBLK), dim3(NTHR),
                                               args, 0, stream);
  if (lerr != hipSuccess) {
    // flag/atomic sync only (no grid.sync); 1 block/CU resources + grid==CU count
    // guarantee co-residency under a plain launch as well.
    hipLaunchKernelGGL(seq2seq_pipe, dim3(NBLK), dim3(NTHR), 0, stream,
                       src, attn_w, attn_b, attn_v, fc_w, fc_b, out, ib);
  }
}

// Round 11
// 6599.282 us; speedup vs baseline: 1.1921x; 1.0651x over previous
//
#include <hip/hip_runtime.h>
#include <hip/hip_fp16.h>
#include <math.h>

#define BB 512
#define HH 256
#define SS 168
#define TT 24
#define NBLK 256
#define NTHR 512
typedef unsigned long long ull;
typedef unsigned short u16;
#define BH 131072ull  // 512*256

// ---- int area (from ws): per-group SLOT flags at ib + g*4096 ----
// 64B-strided slots (16 ints), one WRITER block each, plain stores (no RMW).
//   f_e0 [0..256):    16 slots (rh*8+gi)  enc layer0, val = t+1
//   f_e1 [256..512):  16 slots (rh*8+gi)  enc layer1, val = t+1
//   f_pr [512..1024): 32 slots (m)        proj done,  val = 1
//   f_a  [1024..1536):32 slots (m)        dec attn,   val = t+1
//   f_h0 [1536..1792):16 slots (m)        dec cell0,  val = t+1
//   f_h1 [1792..2048):16 slots (m-16)     dec cell1,  val = t+1
// ---- float offsets from fb = (float*)ws + 65536 ---- (r7/r10 map, unchanged)
#define O_Y0  0ull
#define O_H1  262144ull
#define O_H0  524288ull
#define O_CTX 786432ull   // 512 x 288 (cols 0..255 ctx, col 256 pred)
#define O_W0  933888ull   // whi0 [1024][320] bf16, wlo0 follows (163840 fl each)
#define O_W1  1261568ull  // bf16 planes [1024][512]: whi1,wlo1,dhi0,dlo0,dhi1,dlo1 (262144 fl each)
#define O_WP  2834432ull  // dec cell0 pred column [1024] f32
#define O_WDT 2835456ull  // Wd^T [256][256] f32
#define O_BP  2900992ull  // packed biases 4x1024 (e0,e1,d0,d1)
#define O_E16 2905088ull  // half[512][168][256]
#define O_P16 13915136ull // half[512][168][256]

typedef float f32x4 __attribute__((ext_vector_type(4)));
typedef float v2f __attribute__((ext_vector_type(2)));
typedef unsigned int ru4 __attribute__((ext_vector_type(4)));  // 8 bf16 raw (4 VGPR)

__device__ __forceinline__ float sigf(float x) { return 1.f / (1.f + expf(-x)); }

#define AR __ATOMIC_RELAXED
#define SCA __HIP_MEMORY_SCOPE_AGENT
__device__ __forceinline__ int aLd(const int* p) { return __hip_atomic_load(p, AR, SCA); }

// ---- UC transport: relaxed agent-scope (coherence-point) ops, no fences ----
__device__ __forceinline__ float2 ld2(const float* p) {
  ull raw = __hip_atomic_load((const ull*)p, AR, SCA);
  float2 v; v.x = __uint_as_float((unsigned)raw); v.y = __uint_as_float((unsigned)(raw >> 32));
  return v;
}
__device__ __forceinline__ float ld1(const float* p) {
  unsigned raw = __hip_atomic_load((const unsigned*)p, AR, SCA);
  return __uint_as_float(raw);
}
__device__ __forceinline__ void st1(float* p, float v) {
  __hip_atomic_store((unsigned*)p, __float_as_uint(v), AR, SCA);
}
__device__ __forceinline__ void sth(__half* p, __half v) {
  __hip_atomic_store((unsigned short*)p, __half_as_ushort(v), AR, SCA);
}
__device__ __forceinline__ void stu(unsigned* p, unsigned v) {
  __hip_atomic_store(p, v, AR, SCA);
}

// ---- manual-vmcnt loads (r0/r7-proven pattern: asm + "memory" clobber) ----
__device__ __forceinline__ void ld_h2(const float* p, v2f& a) {   // UC: 2 f32
  asm volatile("global_load_dwordx2 %0, %1, off sc0 sc1"
               : "=&v"(a) : "v"(p) : "memory");
}
__device__ __forceinline__ void ld_w2(const u16* ph, const u16* pl, ru4& h, ru4& l) {
  asm volatile("global_load_dwordx4 %0, %2, off\n\t"
               "global_load_dwordx4 %1, %3, off"
               : "=&v"(h), "=&v"(l) : "v"(ph), "v"(pl) : "memory");
}
#define VMW(n) asm volatile("s_waitcnt vmcnt(" #n ")" ::: "memory")

// inline-asm MFMA (r4/r6/r7-proven): D(=C) += A*B; VGPR C/D ok on gfx950.
#define MFMA(d, a, b) asm volatile("v_mfma_f32_16x16x32_bf16 %0, %1, %2, %0" \
                                   : "+v"(d) : "v"(a), "v"(b))
// force value materialization (compiler emits its waitcnt HERE, before our asm loads)
#define TOUCH(x) asm volatile("" : "+v"(x))

// ---- slot-flag sync: writer-exclusive slots, parallel lane polling, no RMW ----
#define SSTR 16   // slot stride in ints (64B)
__device__ __forceinline__ void arrive_slot(int* slot, int val) {
  asm volatile("s_waitcnt vmcnt(0)" ::: "memory");  // data at coherence point first
  __syncthreads();
  if (threadIdx.x == 0) __hip_atomic_store(slot, val, AR, SCA);
}
__device__ __forceinline__ void wait_slots(const int* base, int n, int tgt) {
  if (threadIdx.x < 64) {
    const int lane = threadIdx.x;
    const int* p = base + lane * SSTR;
    for (;;) {
      const int ok = (lane >= n) || (aLd(p) >= tgt);
      if (__all(ok)) break;
      __builtin_amdgcn_s_sleep(1);
    }
  }
  __syncthreads();
}
__device__ __forceinline__ void wait_slots2(const int* a, int na, const int* b, int nb, int tgt) {
  if (threadIdx.x < 64) {
    const int lane = threadIdx.x;
    const int* p = (lane < na) ? (a + lane * SSTR)
                 : (lane < na + nb) ? (b + (lane - na) * SSTR) : (const int*)nullptr;
    for (;;) {
      const int ok = (p == nullptr) || (aLd(p) >= tgt);
      if (__all(ok)) break;
      __builtin_amdgcn_s_sleep(1);
    }
  }
  __syncthreads();
}

// ---- LDS ----
struct SMT {
  union {
    struct { unsigned WsH[128][20]; unsigned WsL[128][20]; float Ht[32][36]; } m;  // mfma gemm
    struct { float As[32][65];  float Bs[32][65]; } g;   // enc_proj gemm
    struct { float h1s[256], qs[256], vs[256], sc[192], ctxs[1024], sred[4]; } at;
  };
};

__device__ __forceinline__ void fma16(float acc[4][4], const float4 hv, const float4 wv) {
  acc[0][0] += hv.x * wv.x; acc[0][1] += hv.x * wv.y; acc[0][2] += hv.x * wv.z; acc[0][3] += hv.x * wv.w;
  acc[1][0] += hv.y * wv.x; acc[1][1] += hv.y * wv.y; acc[1][2] += hv.y * wv.z; acc[1][3] += hv.y * wv.w;
  acc[2][0] += hv.z * wv.x; acc[2][1] += hv.z * wv.y; acc[2][2] += hv.z * wv.z; acc[2][3] += hv.z * wv.w;
  acc[3][0] += hv.w * wv.x; acc[3][1] += hv.w * wv.y; acc[3][2] += hv.w * wv.z; acc[3][3] += hv.w * wv.w;
}

// ---- fp32 -> bf16 hi/lo split, RNE (unbiased; dropped lo*lo ~2^-18 relative) ----
__device__ __forceinline__ unsigned rne16(unsigned u) {
  return (u + 0x7fffu + ((u >> 16) & 1u)) >> 16;
}
__device__ __forceinline__ void split8v(const f32x4 a, const f32x4 b, ru4& hi, ru4& lo) {
#pragma unroll
  for (int j = 0; j < 4; j++) {
    const float x = (j < 2) ? a[2 * j] : b[2 * j - 4];
    const float y = (j < 2) ? a[2 * j + 1] : b[2 * j - 3];
    const unsigned hx = rne16(__float_as_uint(x)), hy = rne16(__float_as_uint(y));
    const float rx = x - __uint_as_float(hx << 16);
    const float ry = y - __uint_as_float(hy << 16);
    hi[j] = (hx & 0xffffu) | (hy << 16);
    lo[j] = (rne16(__float_as_uint(rx)) & 0xffffu) | (rne16(__float_as_uint(ry)) << 16);
  }
}

// ---------------------------------------------------------------------------
// Per-chunk MFMA compute, 8-wave block (r10-validated): wave (w1 row-half,
// wq gc-quarter) does 16 rows x 32 gc via 2 gate-groups. 6 MFMAs.
// ---------------------------------------------------------------------------
__device__ __forceinline__ void comp_mfma(SMT& sm, int wq, int w1, int l15, int l4,
                                          f32x4 acc[2])
{
  const int hr = w1 * 16 + l15;
  const f32x4 hv0 = *(const f32x4*)&sm.m.Ht[hr][l4 * 8];
  const f32x4 hv1 = *(const f32x4*)&sm.m.Ht[hr][l4 * 8 + 4];
  ru4 bhi, blo;
  split8v(hv0, hv1, bhi, blo);
  asm volatile("s_nop 1" : "+v"(bhi), "+v"(blo));   // VALU->MFMA RAW spacing
#pragma unroll
  for (int g = 0; g < 2; g++) {
    const int cr = wq * 32 + g * 16 + l15;
    ru4 ah = *(const ru4*)&sm.m.WsH[cr][l4 * 4];
    ru4 al = *(const ru4*)&sm.m.WsL[cr][l4 * 4];
    MFMA(acc[g], ah, bhi);
    MFMA(acc[g], ah, blo);
    MFMA(acc[g], al, bhi);
  }
}

// ---------------------------------------------------------------------------
// Software-pipelined gate-GEMM over NC 32-K chunks (r10-validated).
// ---------------------------------------------------------------------------
#define STW(wh, wl) do { \
  *(ru4*)&sm.m.WsH[cgt][kt * 4] = (wh); \
  *(ru4*)&sm.m.WsL[cgt][kt * 4] = (wl); } while (0)
#define STH(a) do { \
  sm.m.Ht[r][p2 * 2] = (a)[0]; sm.m.Ht[r][p2 * 2 + 1] = (a)[1]; } while (0)

__device__ void gemm_pipe(const u16* wbh, const u16* wbl,
                          const float* hb0, const float* hb1,
                          int NC, int nc0, f32x4 acc[2], SMT& sm,
                          int wq, int w1, int l15, int l4)
{
  const int tid = threadIdx.x;
  const int r = tid & 31, p2 = tid >> 5;          // H staging coords (p2 0..15)
  const int cgt = tid & 127, kt = tid >> 7;       // W staging coords (kt 0..3)
  const float* h1p = hb1 - (ull)nc0 * 32;
#define HBk(k) (((k) < nc0) ? (hb0 + (k) * 32) : (h1p + (k) * 32))
  ru4 wh0, wl0, wh1, wl1, wh2, wl2, wh3, wl3;
  v2f h0, h1, h2, h3;
  ld_w2(wbh,      wbl,      wh0, wl0);
  ld_h2(HBk(0), h0);
  ld_w2(wbh + 32, wbl + 32, wh1, wl1);
  ld_h2(HBk(1), h1);
  ld_h2(HBk(2), h2);
  for (int c = 0; c < NC; c += 4) {
    // ---- body 0: chunk c ----
    VMW(4);
    STW(wh0, wl0); STH(h0);
    __syncthreads();
    ld_w2(wbh + (c + 2) * 32, wbl + (c + 2) * 32, wh2, wl2);
    ld_h2(HBk(c + 3), h3);
    comp_mfma(sm, wq, w1, l15, l4, acc);
    __syncthreads();
    // ---- body 1: chunk c+1 ----
    VMW(4);
    STW(wh1, wl1); STH(h1);
    __syncthreads();
    ld_w2(wbh + (c + 3) * 32, wbl + (c + 3) * 32, wh3, wl3);
    ld_h2(HBk(c + 4), h0);
    comp_mfma(sm, wq, w1, l15, l4, acc);
    __syncthreads();
    // ---- body 2: chunk c+2 ----
    VMW(4);
    STW(wh2, wl2); STH(h2);
    __syncthreads();
    ld_w2(wbh + (c + 4) * 32, wbl + (c + 4) * 32, wh0, wl0);
    ld_h2(HBk(c + 5), h1);
    comp_mfma(sm, wq, w1, l15, l4, acc);
    __syncthreads();
    // ---- body 3: chunk c+3 ----
    VMW(4);
    STW(wh3, wl3); STH(h3);
    __syncthreads();
    ld_w2(wbh + (c + 5) * 32, wbl + (c + 5) * 32, wh1, wl1);
    ld_h2(HBk(c + 6), h2);
    comp_mfma(sm, wq, w1, l15, l4, acc);
    __syncthreads();
  }
  asm volatile("s_waitcnt vmcnt(0)" ::: "memory");  // junk drained before reg reuse
  // MFMA->VALU RAW spacing before epilogue reads acc
  asm volatile("s_nop 7\n\ts_nop 7" : "+v"(acc[0]), "+v"(acc[1]));
#undef HBk
}

// ---- epilogue: lane owns (myrow, u = ubase+g*4+l4), g<2; gates = acc[g][0..3] ----
__device__ __forceinline__ void lstm_epi2(f32x4 acc[2], float cR[2], int row, int ubase, int l4,
                                          float* hout, __half* e16, int sstep)
{
#pragma unroll
  for (int g = 0; g < 2; g++) {
    const int u = ubase + g * 4 + l4;
    const float iv = sigf(acc[g][0]), fv = sigf(acc[g][1]);
    const float gv = tanhf(acc[g][2]), ov = sigf(acc[g][3]);
    const float cn = fv * cR[g] + iv * gv;
    cR[g] = cn;
    const float hn = ov * tanhf(cn);
    st1(hout + (ull)row * 256 + u, hn);
    if (e16) sth(e16 + ((ull)row * SS + sstep) * 256 + u, __float2half(hn));
  }
}

// ---- attention + fc for one batch row (UC transport), 512-thread (r10) ----
__device__ void attn_fc(int row, int t, int slot, const float* h1r, const float* wdT,
                        const float* attn_b, const float* attn_v,
                        const __half* P16, const __half* E16,
                        const float* fc_w, const float* fc_b,
                        float* ctxb, float* out, SMT& sm)
{
  const int tid = threadIdx.x;
  __syncthreads();
  if (tid < 128) {
    float2 v = ld2(h1r + (ull)slot * BH + (ull)row * 256 + tid * 2);
    sm.at.h1s[tid * 2] = v.x; sm.at.h1s[tid * 2 + 1] = v.y;
  }
  __syncthreads();
  if (t >= 1 && tid < 64) {
    float a = 0.f;
#pragma unroll
    for (int j = 0; j < 4; j++) a += sm.at.h1s[tid + 64 * j] * fc_w[tid + 64 * j];
#pragma unroll
    for (int m = 32; m >= 1; m >>= 1) a += __shfl_xor(a, m, 64);
    if (tid == 0) {
      const float p = a + fc_b[0];
      out[(ull)row * TT + (t - 1)] = p;
      st1(ctxb + (ull)row * 288 + 256, p);
    }
  }
  if (t >= TT) return;
  if (tid < 256) {
    float qv = attn_b[tid];
    for (int k = 0; k < 256; k += 4) {
      qv += sm.at.h1s[k]     * wdT[(ull)(k)     * 256 + tid];
      qv += sm.at.h1s[k + 1] * wdT[(ull)(k + 1) * 256 + tid];
      qv += sm.at.h1s[k + 2] * wdT[(ull)(k + 2) * 256 + tid];
      qv += sm.at.h1s[k + 3] * wdT[(ull)(k + 3) * 256 + tid];
    }
    sm.at.qs[tid] = qv;
    sm.at.vs[tid] = attn_v[tid];
  }
  __syncthreads();
  const int wv = tid >> 6, lane = tid & 63;
  for (int s = wv; s < SS; s += 8) {
    const __half2* Pr = (const __half2*)(P16 + ((ull)row * SS + s) * 256);
    float a = 0.f;
#pragma unroll
    for (int jj = 0; jj < 2; jj++) {
      const int i2 = lane + 64 * jj;
      const float2 pv = __half22float2(Pr[i2]);
      const int g0 = i2 * 2;
      a += sm.at.vs[g0] * tanhf(pv.x + sm.at.qs[g0]);
      a += sm.at.vs[g0 + 1] * tanhf(pv.y + sm.at.qs[g0 + 1]);
    }
#pragma unroll
    for (int m = 32; m >= 1; m >>= 1) a += __shfl_xor(a, m, 64);
    if (lane == 0) sm.at.sc[s] = a;
  }
  __syncthreads();
  if (tid < 64) {
    float m = -1e30f;
    for (int i = tid; i < SS; i += 64) m = fmaxf(m, sm.at.sc[i]);
#pragma unroll
    for (int mm = 32; mm >= 1; mm >>= 1) m = fmaxf(m, __shfl_xor(m, mm, 64));
    if (tid == 0) sm.at.sred[0] = m;
  }
  __syncthreads();
  const float smax = sm.at.sred[0];
  if (tid < SS) sm.at.sc[tid] = expf(sm.at.sc[tid] - smax);
  __syncthreads();
  if (tid < 64) {
    float ssum = 0.f;
    for (int i = tid; i < SS; i += 64) ssum += sm.at.sc[i];
#pragma unroll
    for (int mm = 32; mm >= 1; mm >>= 1) ssum += __shfl_xor(ssum, mm, 64);
    if (tid == 0) sm.at.sred[1] = ssum;
  }
  __syncthreads();
  const float rinv = 1.f / sm.at.sred[1];
  const int u2 = tid & 127, sh = tid >> 7;   // sh 0..3, 42 s each
  float cx = 0.f, cy = 0.f;
  for (int s = sh * 42; s < sh * 42 + 42; s++) {
    const float w = sm.at.sc[s] * rinv;
    const float2 ev = __half22float2(*(const __half2*)(E16 + ((ull)row * SS + s) * 256 + u2 * 2));
    cx += w * ev.x; cy += w * ev.y;
  }
  sm.at.ctxs[sh * 256 + u2 * 2] = cx;
  sm.at.ctxs[sh * 256 + u2 * 2 + 1] = cy;
  __syncthreads();
  if (tid < 256)
    st1(ctxb + (ull)row * 288 + tid,
        sm.at.ctxs[tid] + sm.at.ctxs[256 + tid] + sm.at.ctxs[512 + tid] + sm.at.ctxs[768 + tid]);
}

// ---- enc_proj 64x64 gemm tile (lower 256 threads active; upper barrier-only) ----
__device__ void proj_tile(const __half* E16, const float* attn_w, __half* P16,
                          int m0, int n0, SMT& sm)
{
  const int tid = threadIdx.x;
  const bool act = tid < 256;
  const int mq = tid & 15, nq = (tid >> 4) & 15;
  const int li = tid & 63, kq = (tid >> 6) & 3;
  float acc[4][4] = {{0.f}};
  for (int k0 = 0; k0 < 256; k0 += 32) {
    if (act) {
      float4 raw = *(const float4*)(E16 + (ull)(m0 + li) * 256 + k0 + kq * 8);
      const __half* hp = (const __half*)&raw;
#pragma unroll
      for (int i = 0; i < 8; i++) sm.g.As[kq * 8 + i][li] = __half2float(hp[i]);
      const float* gb = attn_w + (ull)(n0 + li) * 512 + k0 + kq * 8;
      const float4 v0 = *(const float4*)gb, v1 = *(const float4*)(gb + 4);
      sm.g.Bs[kq * 8 + 0][li] = v0.x; sm.g.Bs[kq * 8 + 1][li] = v0.y;
      sm.g.Bs[kq * 8 + 2][li] = v0.z; sm.g.Bs[kq * 8 + 3][li] = v0.w;
      sm.g.Bs[kq * 8 + 4][li] = v1.x; sm.g.Bs[kq * 8 + 5][li] = v1.y;
      sm.g.Bs[kq * 8 + 6][li] = v1.z; sm.g.Bs[kq * 8 + 7][li] = v1.w;
    }
    __syncthreads();
    if (act) {
#pragma unroll 8
      for (int kk = 0; kk < 32; kk++) {
        const float4 a4 = *(const float4*)&sm.g.As[kk][mq * 4];
        const float4 b4 = *(const float4*)&sm.g.Bs[kk][nq * 4];
        fma16(acc, a4, b4);
      }
    }
    __syncthreads();
  }
  if (act) {
#pragma unroll
    for (int i = 0; i < 4; i++) {
      const int m = m0 + mq * 4 + i;
#pragma unroll
      for (int j = 0; j < 2; j++) {
        __half2 h2; h2.x = __float2half(acc[i][j * 2]); h2.y = __float2half(acc[i][j * 2 + 1]);
        stu((unsigned*)(P16 + (ull)m * 256 + n0 + nq * 4) + j, *(unsigned*)&h2);
      }
    }
  }
}

// ---------------------------------------------------------------------------
__global__ __launch_bounds__(512, 1) void seq2seq_pipe(
    const float* __restrict__ src,
    const float* __restrict__ attn_w, const float* __restrict__ attn_b,
    const float* __restrict__ attn_v,
    const float* __restrict__ fc_w, const float* __restrict__ fc_b,
    float* __restrict__ out, int* __restrict__ ib)
{
  __shared__ SMT sm;
  const int blk = blockIdx.x;
  const int tid = threadIdx.x;
  float* fb = (float*)ib + 65536;
  float* y0r  = fb + O_Y0;
  float* h1r  = fb + O_H1;
  float* h0r  = fb + O_H0;
  float* zb   = h0r + BH;          // zeroed by init; overwritten first at dec t=1
  float* ctxb = fb + O_CTX;
  const u16* whi0 = (const u16*)(fb + O_W0);
  const u16* wlo0 = whi0 + 1024ull * 320;
  const u16* whi1 = (const u16*)(fb + O_W1);
  const u16* wlo1 = whi1 + 1024ull * 512;
  const u16* dhi0 = whi1 + 2ull * 1024 * 512;
  const u16* dlo0 = whi1 + 3ull * 1024 * 512;
  const u16* dhi1 = whi1 + 4ull * 1024 * 512;
  const u16* dlo1 = whi1 + 5ull * 1024 * 512;
  const float* wp  = fb + O_WP;    // dec cell0 pred column [1024]
  const float* wdT = fb + O_WDT;
  const float* bp  = fb + O_BP;
  __half* E16 = (__half*)(fb + O_E16);
  __half* P16 = (__half*)(fb + O_P16);
  const int g = blk >> 5, m = blk & 31;
  const int rowg = g * 64;
  int* gf = ib + g * 4096;
  int* f_e0 = gf;            // 16 slots (rh*8+gi)
  int* f_e1 = gf + 256;      // 16 slots
  int* f_pr = gf + 512;      // 32 slots (m)
  int* f_a  = gf + 1024;     // 32 slots (m)
  int* f_h0 = gf + 1536;     // 16 slots (m)
  int* f_h1 = gf + 1792;     // 16 slots (m-16)

  // tile geometry: block = 32 rows x 128 gate-cols; 8 waves: 16 rows x 32 gc
  const int lm = (m < 16) ? m : (m - 16);
  const int rh = lm & 1, gi = lm >> 1;          // row-half, gc-tile
  const int row0 = rowg + rh * 32;
  const int gc0 = gi * 128;
  const int w = tid >> 6;
  const int l15 = tid & 15, l4 = (tid >> 4) & 3;
  const int w1 = w & 1, wq = w >> 1;            // row-half, gc-quarter
  const int gcw = gc0 + wq * 32;                // wave's 32 gate-cols
  const int myrow = row0 + w1 * 16 + l15;       // this lane's batch row
  const int ubase = gcw >> 2;                   // u = ubase + g*4 + l4
  const int r = tid & 31;                       // staging row
  const int cgt = tid & 127, kt = tid >> 7;     // W staging coords (kt 0..3)

  int* my_enc_slot = (m < 16 ? f_e0 : f_e1) + (rh * 8 + gi) * SSTR;
  const int* e0h = f_e0 + rh * 8 * SSTR;
  const int* e1h = f_e1 + rh * 8 * SSTR;

  float cReg[2] = {0.f, 0.f};

  // ======== encoder: wavefront; per-(layer,row-half) slot flags, fan-in 8 ========
  for (int t = 0; t <= SS; t++) {
    if (t) wait_slots2(e0h, 8, e1h, 8, t);   // step t-1 done (both layers, same half)
    if (m < 16) {
      if (t < SS) {
        f32x4 acc[2];
#pragma unroll
        for (int gg = 0; gg < 2; gg++) {
          acc[gg] = *(const f32x4*)(bp + gcw + gg * 16 + l4 * 4);
          TOUCH(acc[gg]);
        }
        // ---- x chunk: W k 0..31 (x wts + zero pad), Ht cols 16..31 zeroed ----
        {
          ru4 wxh, wxl;
          ld_w2(whi0 + (ull)(gc0 + cgt) * 320 + kt * 8,
                wlo0 + (ull)(gc0 + cgt) * 320 + kt * 8, wxh, wxl);
          VMW(0);
          *(ru4*)&sm.m.WsH[cgt][kt * 4] = wxh;
          *(ru4*)&sm.m.WsL[cgt][kt * 4] = wxl;
          const int f = tid >> 5;   // 0..15
          sm.m.Ht[r][f]      = src[((ull)(row0 + r) * SS + t) * 16 + f];
          sm.m.Ht[r][f + 16] = 0.f;
          __syncthreads();
          comp_mfma(sm, wq, w1, l15, l4, acc);
          __syncthreads();
        }
        // ---- h chunks: W k 32.., h[0..255] ----
        const float* ysrc = (t == 0) ? zb : (y0r + (ull)((t + 1) & 1) * BH);
        const float* hb0 = ysrc + (ull)(row0 + r) * 256 + (tid >> 5) * 2;
        gemm_pipe(whi0 + (ull)(gc0 + cgt) * 320 + 32 + kt * 8,
                  wlo0 + (ull)(gc0 + cgt) * 320 + 32 + kt * 8,
                  hb0, hb0, 8, 8, acc, sm, wq, w1, l15, l4);
        lstm_epi2(acc, cReg, myrow, ubase, l4, y0r + (ull)(t & 1) * BH, nullptr, 0);
      }
    } else {
      if (t >= 1) {
        const int s = t - 1;
        f32x4 acc[2];
#pragma unroll
        for (int gg = 0; gg < 2; gg++) {
          acc[gg] = *(const f32x4*)(bp + 1024 + gcw + gg * 16 + l4 * 4);
          TOUCH(acc[gg]);
        }
        const float* ysrc = y0r + (ull)(s & 1) * BH;
        const float* hsrc = (s == 0) ? zb : (h1r + (ull)((s + 1) & 1) * BH);
        const float* hb0 = ysrc + (ull)(row0 + r) * 256 + (tid >> 5) * 2;
        const float* hb1 = hsrc + (ull)(row0 + r) * 256 + (tid >> 5) * 2;  // r0 convention: NO pre-offset
        gemm_pipe(whi1 + (ull)(gc0 + cgt) * 512 + kt * 8,
                  wlo1 + (ull)(gc0 + cgt) * 512 + kt * 8,
                  hb0, hb1, 16, 8, acc, sm, wq, w1, l15, l4);
        lstm_epi2(acc, cReg, myrow, ubase, l4, h1r + (ull)(s & 1) * BH, E16, s);
      }
    }
    arrive_slot(my_enc_slot, t + 1);
  }

  // ======== enc_proj: wait all layer1 done (E16 complete), 21 tiles/block ========
  wait_slots(f_e1, 16, SS + 1);
  {
    const int em0 = rowg * SS;
    for (int tau = m; tau < 672; tau += 32)
      proj_tile(E16, attn_w, P16, em0 + (tau >> 2) * 64, (tau & 3) * 64, sm);
  }
  arrive_slot(f_pr + m * SSTR, 1);

  // ======== decoder (cReg NOT reset: cell0/cell1 inherit enc-final c0e/c1e
  //          under the identical lane->(row,u) partition) ========
  for (int t = 0; t <= TT; t++) {
    if (t == 0) wait_slots(f_pr, 32, 1);
    else wait_slots(f_h1, 16, t);            // cell1 step t-1 done
    const int slot = (t + 1) & 1;
    attn_fc(rowg + 2 * m,     t, slot, h1r, wdT, attn_b, attn_v, P16, E16, fc_w, fc_b, ctxb, out, sm);
    attn_fc(rowg + 2 * m + 1, t, slot, h1r, wdT, attn_b, attn_v, P16, E16, fc_w, fc_b, ctxb, out, sm);
    if (t == TT) break;
    arrive_slot(f_a + m * SSTR, t + 1);
    if (m < 16) {
      // ---- dec cell0: x = [ctx(256) | h0prev(256) | pred(1)] ----
      wait_slots(f_a, 32, t + 1);            // attn step t done (ctx ready)
      if (t) wait_slots(f_h0, 16, t);        // cell0 step t-1 done (h0prev ready)
      f32x4 acc[2];
#pragma unroll
      for (int gg = 0; gg < 2; gg++) {
        acc[gg] = *(const f32x4*)(bp + 2048 + gcw + gg * 16 + l4 * 4);
        TOUCH(acc[gg]);
      }
      const float* h0src = (t == 0) ? (y0r + BH) : (h0r + (ull)((t + 1) & 1) * BH);
      const float* hb0 = ctxb + (ull)(row0 + r) * 288 + (tid >> 5) * 2;
      const float* hb1 = h0src + (ull)(row0 + r) * 256 + (tid >> 5) * 2;  // NO pre-offset
      gemm_pipe(dhi0 + (ull)(gc0 + cgt) * 512 + kt * 8,
                dlo0 + (ull)(gc0 + cgt) * 512 + kt * 8,
                hb0, hb1, 16, 8, acc, sm, wq, w1, l15, l4);
      const float p = ld1(ctxb + (ull)myrow * 288 + 256);
#pragma unroll
      for (int gg = 0; gg < 2; gg++) {
        const f32x4 wpv = *(const f32x4*)(wp + gcw + gg * 16 + l4 * 4);
        acc[gg] = acc[gg] + wpv * p;
      }
      lstm_epi2(acc, cReg, myrow, ubase, l4, h0r + (ull)(t & 1) * BH, nullptr, 0);
      arrive_slot(f_h0 + m * SSTR, t + 1);
    } else {
      // ---- dec cell1: x = [h0new(256) | h1prev(256)] ----
      wait_slots(f_h0, 16, t + 1);           // cell0 step t done (h0new ready)
      if (t) wait_slots(f_h1, 16, t);        // cell1 step t-1 done (h1prev ready)
      f32x4 acc[2];
#pragma unroll
      for (int gg = 0; gg < 2; gg++) {
        acc[gg] = *(const f32x4*)(bp + 3072 + gcw + gg * 16 + l4 * 4);
        TOUCH(acc[gg]);
      }
      const float* hb0 = h0r + (ull)(t & 1) * BH + (ull)(row0 + r) * 256 + (tid >> 5) * 2;
      const float* hb1 = h1r + (ull)((t + 1) & 1) * BH + (ull)(row0 + r) * 256 + (tid >> 5) * 2;  // NO pre-offset
      gemm_pipe(dhi1 + (ull)(gc0 + cgt) * 512 + kt * 8,
                dlo1 + (ull)(gc0 + cgt) * 512 + kt * 8,
                hb0, hb1, 16, 8, acc, sm, wq, w1, l15, l4);
      lstm_epi2(acc, cReg, myrow, ubase, l4, h1r + (ull)(t & 1) * BH, nullptr, 0);
      arrive_slot(f_h1 + (m - 16) * SSTR, t + 1);
    }
  }
}

// ---------------------------------------------------------------------------
// Init: zero slot flags + zb, split weights (RNE) into bf16 hi/lo planes
// [cg][K] (cg = u*4+gate), pack biases, Wd^T, pred column, seed ctx pred col.
// layer0 KP=320: k<16 x | 16..31 zero | 32..287 h | 288..319 zero.
// ---------------------------------------------------------------------------
__device__ __forceinline__ void split_store(float v, u16* hi, u16* lo, ull i) {
  const unsigned u = __float_as_uint(v);
  const unsigned hb = (u + 0x7fffu + ((u >> 16) & 1u)) >> 16;
  const float rr = v - __uint_as_float(hb << 16);
  const unsigned ur = __float_as_uint(rr);
  const unsigned lb = (ur + 0x7fffu + ((ur >> 16) & 1u)) >> 16;
  hi[i] = (u16)hb; lo[i] = (u16)lb;
}

__global__ void init_all(
    const float* __restrict__ src,
    const float* __restrict__ ewih0, const float* __restrict__ ewhh0, const float* __restrict__ eb0,
    const float* __restrict__ ewih1, const float* __restrict__ ewhh1, const float* __restrict__ eb1,
    const float* __restrict__ dwih0, const float* __restrict__ dwhh0, const float* __restrict__ db0,
    const float* __restrict__ dwih1, const float* __restrict__ dwhh1, const float* __restrict__ db1,
    const float* __restrict__ attn_w, int* __restrict__ ib)
{
  const int gid = blockIdx.x * 256 + threadIdx.x;
  const int NG = 1024 * 256;
  float* fb = (float*)ib + 65536;
  u16* whi0 = (u16*)(fb + O_W0);
  u16* wlo0 = whi0 + 1024ull * 320;
  u16* whi1 = (u16*)(fb + O_W1);
  u16* wlo1 = whi1 + 1024ull * 512;
  u16* dhi0 = whi1 + 2ull * 1024 * 512;
  u16* dlo0 = whi1 + 3ull * 1024 * 512;
  u16* dhi1 = whi1 + 4ull * 1024 * 512;
  u16* dlo1 = whi1 + 5ull * 1024 * 512;
  float* wpd = fb + O_WP;

  for (int i = gid; i < 32768; i += NG) ib[i] = 0;                  // slot flags (8 groups x 4096)
  for (int i = gid; i < (int)BH; i += NG) fb[O_H0 + BH + i] = 0.f;  // zb
  for (int i = gid; i < 1024 * 320; i += NG) {
    const int cg = i / 320, k = i - cg * 320, j = (cg & 3) * 256 + (cg >> 2);
    float v = 0.f;
    if (k < 16) v = ewih0[(ull)j * 16 + k];
    else if (k >= 32 && k < 288) v = ewhh0[(ull)j * 256 + (k - 32)];
    split_store(v, whi0, wlo0, i);
  }
  for (int i = gid; i < 1024 * 512; i += NG) {
    const int cg = i >> 9, k = i & 511, j = (cg & 3) * 256 + (cg >> 2);
    split_store((k < 256) ? ewih1[(ull)j * 256 + k] : ewhh1[(ull)j * 256 + k - 256], whi1, wlo1, i);
    split_store((k < 256) ? dwih0[(ull)j * 257 + 1 + k] : dwhh0[(ull)j * 256 + k - 256], dhi0, dlo0, i);
    split_store((k < 256) ? dwih1[(ull)j * 256 + k] : dwhh1[(ull)j * 256 + k - 256], dhi1, dlo1, i);
  }
  for (int i = gid; i < 1024; i += NG) {
    const int j = (i & 3) * 256 + (i >> 2);
    wpd[i] = dwih0[(ull)j * 257];
  }
  for (int i = gid; i < 256 * 256; i += NG) {
    const int k = i >> 8, gg = i & 255;
    fb[O_WDT + i] = attn_w[(ull)gg * 512 + 256 + k];
  }
  for (int i = gid; i < 4096; i += NG) {
    const int set = i >> 10, cg = i & 1023, j = (cg & 3) * 256 + (cg >> 2);
    const float* bsrc = (set == 0) ? eb0 : (set == 1) ? eb1 : (set == 2) ? db0 : db1;
    fb[O_BP + i] = bsrc[j];
  }
  for (int i = gid; i < 512; i += NG)
    fb[O_CTX + (ull)i * 288 + 256] = src[((ull)i * SS + 167) * 16 + 15];
}

extern "C" void kernel_launch(void* const* d_in, const int* in_sizes, int n_in,
                              void* d_out, int out_size, void* d_ws, size_t ws_size,
                              hipStream_t stream)
{
  const float* src    = (const float*)d_in[0];
  const float* ewih0  = (const float*)d_in[1];
  const float* ewhh0  = (const float*)d_in[2];
  const float* eb0    = (const float*)d_in[3];
  const float* ewih1  = (const float*)d_in[4];
  const float* ewhh1  = (const float*)d_in[5];
  const float* eb1    = (const float*)d_in[6];
  const float* dwih0  = (const float*)d_in[7];
  const float* dwhh0  = (const float*)d_in[8];
  const float* db0    = (const float*)d_in[9];
  const float* dwih1  = (const float*)d_in[10];
  const float* dwhh1  = (const float*)d_in[11];
  const float* db1    = (const float*)d_in[12];
  const float* attn_w = (const float*)d_in[13];
  const float* attn_b = (const float*)d_in[14];
  const float* attn_v = (const float*)d_in[15];
  // d_in[16] pos_bias: post-tanh, uniform over s -> softmax-invariant, unused.
  const float* fc_w   = (const float*)d_in[17];
  const float* fc_b   = (const float*)d_in[18];
  float* out = (float*)d_out;
  int* ib    = (int*)d_ws;

  init_all<<<1024, 256, 0, stream>>>(src, ewih0, ewhh0, eb0, ewih1, ewhh1, eb1,
                                     dwih0, dwhh0, db0, dwih1, dwhh1, db1, attn_w, ib);

  void* args[] = {
    (void*)&src, (void*)&attn_w, (void*)&attn_b, (void*)&attn_v,
    (void*)&fc_w, (void*)&fc_b, (void*)&out, (void*)&ib,
  };
  hipError_t lerr = hipLaunchCooperativeKernel((const void*)seq2seq_pipe, dim3(NBLK), dim3(NTHR),
                                               args, 0, stream);
  if (lerr != hipSuccess) {
    // flag/atomic sync only (no grid.sync); 1 block/CU resources + grid==CU count
    // guarantee co-residency under a plain launch as well.
    hipLaunchKernelGGL(seq2seq_pipe, dim3(NBLK), dim3(NTHR), 0, stream,
                       src, attn_w, attn_b, attn_v, fc_w, fc_b, out, ib);
  }
}